// Round 10
// baseline (364.820 us; speedup 1.0000x reference)
//
#include <hip/hip_runtime.h>
#include <math.h>

#define Nn 100000
#define Ee 1600000
#define EP 1700000   /* Ee + Nn self loops */
#define NC 40
#define SLOPE 0.2f
#define GSZ 256      /* nodes per bucket */
#define NBUK 391     /* ceil(Nn/GSZ) */
#define CAPB 8192    /* padded capacity per bucket */
#define CHA 8192     /* edges per partition block */
#define NBA ((EP + CHA - 1) / CHA)
#define G1B ((Nn + 255) / 256)   /* 256 nodes per fused gemm block (4 x 64-node groups) */

typedef short bf16x8 __attribute__((ext_vector_type(8)));
typedef float f32x4 __attribute__((ext_vector_type(4)));
typedef unsigned int u32x4 __attribute__((ext_vector_type(4)));

// ---------- bf16 helpers ----------

__device__ __forceinline__ unsigned short f2bf(float f) {
    unsigned u = __float_as_uint(f);
    unsigned r = u + 0x7FFFu + ((u >> 16) & 1u);
    return (unsigned short)(r >> 16);
}
__device__ __forceinline__ float bf2f(unsigned short u) {
    return __uint_as_float(((unsigned)u) << 16);
}

// ---------------- weight cast/transpose + w~ vectors + bukcnt zero + rs[Nn] ----------------

__global__ void castW_kernel(const float* __restrict__ W1, const float* __restrict__ r1W,
                             const float* __restrict__ W2, const float* __restrict__ r2W,
                             const float* __restrict__ att_s2, const float* __restrict__ att_d2,
                             unsigned short* __restrict__ Wb1t, unsigned short* __restrict__ Wb2t,
                             float* __restrict__ wts, float* __restrict__ wtd,
                             int* __restrict__ bukcnt, int* __restrict__ rs) {
    int tid = blockIdx.x * 256 + threadIdx.x;
    if (tid < 256 * 128) {
        int col = tid >> 7, k = tid & 127;
        float v = (col < 128) ? W1[k * 128 + col] : r1W[k * 128 + (col - 128)];
        Wb1t[col * 128 + k] = f2bf(v);
    } else if (tid < 256 * 128 + 80 * 128) {
        int t2 = tid - 256 * 128;
        int col = t2 >> 7, k = t2 & 127;
        float v = (col < NC) ? W2[k * NC + col] : r2W[k * NC + (col - NC)];
        Wb2t[col * 128 + k] = f2bf(v);
    } else {
        int t3 = tid - 256 * 128 - 80 * 128;
        if (t3 < 128) {
            float s = 0.f;
            for (int c = 0; c < NC; c++) s += W2[t3 * NC + c] * att_s2[c];
            wts[t3] = s;
        } else if (t3 < 256) {
            int k = t3 - 128;
            float s = 0.f;
            for (int c = 0; c < NC; c++) s += W2[k * NC + c] * att_d2[c];
            wtd[k] = s;
        } else {
            int t4 = t3 - 256;
            if (t4 < NBUK) bukcnt[t4] = 0;
            else if (t4 == NBUK) rs[Nn] = EP;
        }
    }
}

// ---------------- fused (1024 threads): partA (8 edges/thread) || gemm1 (4 x 64-node groups) ----------------

__global__ __launch_bounds__(1024) void fused1_kernel(
        const float* __restrict__ x, const unsigned short* __restrict__ Wb1t,
        const float* __restrict__ r1b,
        const float* __restrict__ att_s, const float* __restrict__ att_d,
        unsigned short* __restrict__ h1b, unsigned short* __restrict__ hbufb,
        float* __restrict__ as1, float* __restrict__ ad1,
        const int* __restrict__ ei, int* __restrict__ bukcnt,
        long long* __restrict__ pairs) {
    __shared__ int smem[NBUK * 2];
    if (blockIdx.x < NBA) {
        // ---- partA body: 1024 threads, 8 edges/thread (2 x int4 batches) ----
        int* cntA = smem;
        int* resA = smem + NBUK;
        int t = threadIdx.x;
        for (int i = t; i < NBUK; i += 1024) cntA[i] = 0;
        __syncthreads();
        int e0 = blockIdx.x * CHA;
        int cnt = EP - e0; if (cnt > CHA) cnt = CHA;   // always a multiple of 4

        int4 dd[2];
        #pragma unroll
        for (int p = 0; p < 2; p++) {
            int k = t * 4 + p * 4096;
            int e = e0 + k;
            if (k < cnt) {
                if (e + 3 < Ee) {
                    dd[p] = *(const int4*)(ei + Ee + e);
                } else {
                    dd[p].x = (e     < Ee) ? ei[Ee + e]     : e     - Ee;
                    dd[p].y = (e + 1 < Ee) ? ei[Ee + e + 1] : e + 1 - Ee;
                    dd[p].z = (e + 2 < Ee) ? ei[Ee + e + 2] : e + 2 - Ee;
                    dd[p].w = (e + 3 < Ee) ? ei[Ee + e + 3] : e + 3 - Ee;
                }
            } else {
                dd[p] = (int4){-1, -1, -1, -1};
            }
        }
        #pragma unroll
        for (int p = 0; p < 2; p++) {
            if (dd[p].x >= 0) {
                atomicAdd(&cntA[dd[p].x >> 8], 1);
                atomicAdd(&cntA[dd[p].y >> 8], 1);
                atomicAdd(&cntA[dd[p].z >> 8], 1);
                atomicAdd(&cntA[dd[p].w >> 8], 1);
            }
        }
        __syncthreads();
        if (t < NBUK) {
            int c = cntA[t];
            resA[t] = c ? atomicAdd(&bukcnt[t], c) : 0;
            cntA[t] = 0;
        }
        __syncthreads();
        int4 ss[2];
        #pragma unroll
        for (int p = 0; p < 2; p++) {
            int k = t * 4 + p * 4096;
            int e = e0 + k;
            if (k < cnt) {
                if (e + 3 < Ee) {
                    ss[p] = *(const int4*)(ei + e);
                } else {
                    ss[p].x = (e     < Ee) ? ei[e]     : e     - Ee;
                    ss[p].y = (e + 1 < Ee) ? ei[e + 1] : e + 1 - Ee;
                    ss[p].z = (e + 2 < Ee) ? ei[e + 2] : e + 2 - Ee;
                    ss[p].w = (e + 3 < Ee) ? ei[e + 3] : e + 3 - Ee;
                }
            }
        }
        #pragma unroll
        for (int p = 0; p < 2; p++) {
            int4 d = dd[p];
            if (d.x >= 0) {
                int b0 = d.x >> 8; int r0 = atomicAdd(&cntA[b0], 1);
                pairs[(size_t)b0 * CAPB + resA[b0] + r0] = ((long long)d.x << 32) | (unsigned)ss[p].x;
                int b1 = d.y >> 8; int r1 = atomicAdd(&cntA[b1], 1);
                pairs[(size_t)b1 * CAPB + resA[b1] + r1] = ((long long)d.y << 32) | (unsigned)ss[p].y;
                int b2 = d.z >> 8; int r2 = atomicAdd(&cntA[b2], 1);
                pairs[(size_t)b2 * CAPB + resA[b2] + r2] = ((long long)d.z << 32) | (unsigned)ss[p].z;
                int b3 = d.w >> 8; int r3 = atomicAdd(&cntA[b3], 1);
                pairs[(size_t)b3 * CAPB + resA[b3] + r3] = ((long long)d.w << 32) | (unsigned)ss[p].w;
            }
        }
    } else {
        // ---- gemm1 body: 16 waves = 4 independent 64-node groups (4 waves each) ----
        int lane = threadIdx.x & 63;
        int w8 = threadIdx.x >> 6;      // 0..15
        int g  = w8 >> 2;               // node group 0..3
        int wv = w8 & 3;                // tile-quad within group
        int m = lane & 15, q = lane >> 4;
        int nb = (blockIdx.x - NBA) * 256 + g * 64;

        bf16x8 bw[4][4];
        #pragma unroll
        for (int t = 0; t < 4; t++) {
            const unsigned short* bp = Wb1t + (size_t)((wv * 4 + t) * 16 + m) * 128 + q * 8;
            #pragma unroll
            for (int kk = 0; kk < 4; kk++)
                bw[t][kk] = *(const bf16x8*)(bp + kk * 32);
        }

        #pragma unroll
        for (int ng = 0; ng < 4; ng++) {
            int node = nb + ng * 16 + m;
            int nld = node < Nn ? node : Nn - 1;

            union { unsigned short u[8]; bf16x8 v; } af[4];
            const float* xr = x + (size_t)nld * 128 + q * 8;
            #pragma unroll
            for (int kk = 0; kk < 4; kk++) {
                float4 a0 = *(const float4*)(xr + kk * 32);
                float4 a1 = *(const float4*)(xr + kk * 32 + 4);
                af[kk].u[0] = f2bf(a0.x); af[kk].u[1] = f2bf(a0.y);
                af[kk].u[2] = f2bf(a0.z); af[kk].u[3] = f2bf(a0.w);
                af[kk].u[4] = f2bf(a1.x); af[kk].u[5] = f2bf(a1.y);
                af[kk].u[6] = f2bf(a1.z); af[kk].u[7] = f2bf(a1.w);
            }

            f32x4 acc[4];
            #pragma unroll
            for (int t = 0; t < 4; t++) acc[t] = (f32x4){0.f, 0.f, 0.f, 0.f};
            #pragma unroll
            for (int t = 0; t < 4; t++) {
                #pragma unroll
                for (int kk = 0; kk < 4; kk++)
                    acc[t] = __builtin_amdgcn_mfma_f32_16x16x32_bf16(bw[t][kk], af[kk].v, acc[t], 0, 0, 0);
            }

            if (node < Nn) {
                if (wv < 2) {
                    float psum[4], pdum[4];
                    #pragma unroll
                    for (int t = 0; t < 4; t++) {
                        int c0 = (wv * 4 + t) * 16 + q * 4;
                        ushort4 o;
                        o.x = f2bf(acc[t][0]); o.y = f2bf(acc[t][1]);
                        o.z = f2bf(acc[t][2]); o.w = f2bf(acc[t][3]);
                        *(ushort4*)(h1b + (size_t)node * 128 + c0) = o;
                        float4 s4 = *(const float4*)(att_s + c0);
                        float4 d4 = *(const float4*)(att_d + c0);
                        float ps = acc[t][0] * s4.x + acc[t][1] * s4.y + acc[t][2] * s4.z + acc[t][3] * s4.w;
                        float pd = acc[t][0] * d4.x + acc[t][1] * d4.y + acc[t][2] * d4.z + acc[t][3] * d4.w;
                        ps += __shfl_xor(ps, 16, 64); ps += __shfl_xor(ps, 32, 64);
                        pd += __shfl_xor(pd, 16, 64); pd += __shfl_xor(pd, 32, 64);
                        psum[t] = ps; pdum[t] = pd;
                    }
                    if (q == 0) {
                        float4 o; o.x = psum[0]; o.y = psum[1]; o.z = psum[2]; o.w = psum[3];
                        *(float4*)(as1 + (size_t)node * 8 + wv * 4) = o;
                    } else if (q == 1) {
                        float4 o; o.x = pdum[0]; o.y = pdum[1]; o.z = pdum[2]; o.w = pdum[3];
                        *(float4*)(ad1 + (size_t)node * 8 + wv * 4) = o;
                    }
                } else {
                    #pragma unroll
                    for (int t = 0; t < 4; t++) {
                        int cc0 = ((wv - 2) * 4 + t) * 16 + q * 4;
                        float4 b4 = *(const float4*)(r1b + cc0);
                        ushort4 o;
                        o.x = f2bf(acc[t][0] + b4.x); o.y = f2bf(acc[t][1] + b4.y);
                        o.z = f2bf(acc[t][2] + b4.z); o.w = f2bf(acc[t][3] + b4.w);
                        *(ushort4*)(hbufb + (size_t)node * 128 + cc0) = o;
                    }
                }
            }
        }
    }
}

// ---------------- phase B: 512 threads, inline bucket prefix + per-node rs + CSR scatter ----------------

__global__ __launch_bounds__(512) void partB_kernel(const long long* __restrict__ pairs,
                                                    const int* __restrict__ bukcnt,
                                                    int* __restrict__ rs,
                                                    int* __restrict__ csr) {
    __shared__ int lcnt[GSZ];
    __shared__ int lbase[GSZ];
    __shared__ int bsum[8];
    int b = blockIdx.x;
    int t = threadIdx.x;
    int node0 = b * GSZ;
    int nodes = Nn - node0; if (nodes > GSZ) nodes = GSZ;
    int acc = 0;
    for (int i = t; i < b; i += 512) acc += bukcnt[i];
    #pragma unroll
    for (int st = 1; st < 64; st <<= 1) acc += __shfl_xor(acc, st, 64);
    if ((t & 63) == 0) bsum[t >> 6] = acc;
    if (t < GSZ) lcnt[t] = 0;
    __syncthreads();
    int bb = bsum[0] + bsum[1] + bsum[2] + bsum[3]
           + bsum[4] + bsum[5] + bsum[6] + bsum[7];
    int lo = b * CAPB;
    int hi = lo + bukcnt[b];
    for (int j = lo + t; j < hi; j += 512) {
        int li = (int)(pairs[j] >> 32) - node0;
        atomicAdd(&lcnt[li], 1);
    }
    __syncthreads();
    int c = (t < GSZ) ? lcnt[t] : 0;
    if (t < GSZ) lbase[t] = c;
    __syncthreads();
    #pragma unroll
    for (int off = 1; off < 256; off <<= 1) {
        int u = (t >= off && t < GSZ) ? lbase[t - off] : 0;
        __syncthreads();
        if (t < GSZ) lbase[t] += u;
        __syncthreads();
    }
    if (t < GSZ) {
        int myBase = bb + lbase[t] - c;
        if (t < nodes) rs[node0 + t] = myBase;
        lbase[t] = myBase;
        lcnt[t] = 0;
    }
    __syncthreads();
    for (int j = lo + t; j < hi; j += 512) {
        long long p = pairs[j];
        int li = (int)(p >> 32) - node0;
        int r = atomicAdd(&lcnt[li], 1);
        csr[lbase[li] + r] = (int)(p & 0xffffffffLL);
    }
}

// ---------------- layer 1 gather-aggregate: shuffle-free + csr software pipeline ----------------

__global__ __launch_bounds__(256) void agg1_kernel(
        const int* __restrict__ rs, const int* __restrict__ csr,
        const float* __restrict__ as, const float* __restrict__ ad,
        const unsigned short* __restrict__ h1b, const float* __restrict__ bias,
        const unsigned short* __restrict__ hbufb, unsigned short* __restrict__ hb,
        const float* __restrict__ wts, const float* __restrict__ wtd,
        float* __restrict__ as2, float* __restrict__ ad2) {
    int lane = threadIdx.x & 63, wv = threadIdx.x >> 6;
    int n = blockIdx.x * 4 + wv;
    if (n >= Nn) return;
    int row = rs[n], end = rs[n + 1];
    int slot = lane >> 3;
    int h = lane & 7;
    float adh = ad[n * 8 + h];
    const unsigned short* hcol = h1b + h * 16;

    float a[16];
    #pragma unroll
    for (int i = 0; i < 16; i++) a[i] = 0.f;
    float den = 0.f;

    bool v = slot < end - row;
    int sl = v ? csr[row + slot] : 0;
    for (int j = row; j < end; j += 8) {
        bool cv = v;
        int cur = sl;
        int jn = j + 8;
        if (jn < end) {
            v = slot < end - jn;
            sl = v ? csr[jn + slot] : 0;
        }
        float lg = as[cur * 8 + h] + adh;
        lg = fmaxf(lg, SLOPE * lg);
        float e = cv ? __expf(lg) : 0.f;
        den += e;
        const unsigned short* p = hcol + (size_t)cur * 128;
        u32x4 u0 = *(const u32x4*)(p);
        u32x4 u1 = *(const u32x4*)(p + 8);
        #pragma unroll
        for (int k = 0; k < 4; k++) {
            unsigned u = u0[k];
            a[2 * k]     += e * __uint_as_float(u << 16);
            a[2 * k + 1] += e * __uint_as_float(u & 0xffff0000u);
            unsigned w = u1[k];
            a[8 + 2 * k]     += e * __uint_as_float(w << 16);
            a[8 + 2 * k + 1] += e * __uint_as_float(w & 0xffff0000u);
        }
    }

    den += __shfl_xor(den, 8, 64);
    den += __shfl_xor(den, 16, 64);
    den += __shfl_xor(den, 32, 64);
    float inv = 1.f / den;

    int l3 = (lane >> 3) & 1, l4 = (lane >> 4) & 1, l5 = (lane >> 5) & 1;
    float b8[8];
    #pragma unroll
    for (int i = 0; i < 8; i++) {
        float mine = l3 ? a[i + 8] : a[i];
        float send = l3 ? a[i] : a[i + 8];
        b8[i] = mine + __shfl_xor(send, 8, 64);
    }
    float b4[4];
    #pragma unroll
    for (int i = 0; i < 4; i++) {
        float mine = l4 ? b8[i + 4] : b8[i];
        float send = l4 ? b8[i] : b8[i + 4];
        b4[i] = mine + __shfl_xor(send, 16, 64);
    }
    float c2[2];
    #pragma unroll
    for (int i = 0; i < 2; i++) {
        float mine = l5 ? b4[i + 2] : b4[i];
        float send = l5 ? b4[i] : b4[i + 2];
        c2[i] = mine + __shfl_xor(send, 32, 64);
    }
    int c0 = h * 16 + l3 * 8 + l4 * 4 + l5 * 2;

    float g0 = c2[0] * inv + bias[c0];
    float g1 = c2[1] * inv + bias[c0 + 1];
    unsigned rr = *(const unsigned*)(hbufb + (size_t)n * 128 + c0);
    g0 = (g0 > 0.f ? g0 : __expf(g0) - 1.f) + __uint_as_float(rr << 16);
    g1 = (g1 > 0.f ? g1 : __expf(g1) - 1.f) + __uint_as_float(rr & 0xffff0000u);
    unsigned o = ((unsigned)f2bf(g0)) | (((unsigned)f2bf(g1)) << 16);
    *(unsigned*)(hb + (size_t)n * 128 + c0) = o;
    float2 wsv = *(const float2*)(wts + c0);
    float2 wdv = *(const float2*)(wtd + c0);
    float ps = g0 * wsv.x + g1 * wsv.y;
    float pd = g0 * wdv.x + g1 * wdv.y;
    #pragma unroll
    for (int st = 32; st >= 1; st >>= 1) {
        ps += __shfl_xor(ps, st, 64);
        pd += __shfl_xor(pd, st, 64);
    }
    if (lane == 0) { as2[n] = ps; ad2[n] = pd; }
}

// ---------------- layer 2 GEMM: 64 nodes/block, reg weights, h2b (stride 64) + residual-out ----------------

__global__ __launch_bounds__(320) void gemm2_kernel(
        const unsigned short* __restrict__ hb, const unsigned short* __restrict__ Wb2t,
        const float* __restrict__ r2b,
        unsigned short* __restrict__ h2b, float* __restrict__ outp) {
    int lane = threadIdx.x & 63, wv = threadIdx.x >> 6;   // wv 0..4
    int m = lane & 15, q = lane >> 4;
    int nb = blockIdx.x * 64;

    bf16x8 bw[4];
    const unsigned short* bp = Wb2t + (size_t)(wv * 16 + m) * 128 + q * 8;
    #pragma unroll
    for (int kk = 0; kk < 4; kk++) bw[kk] = *(const bf16x8*)(bp + kk * 32);

    #pragma unroll
    for (int ng = 0; ng < 4; ng++) {
        int node = nb + ng * 16 + m;
        int nld = node < Nn ? node : Nn - 1;
        const unsigned short* hr = hb + (size_t)nld * 128 + q * 8;
        f32x4 acc = (f32x4){0.f, 0.f, 0.f, 0.f};
        #pragma unroll
        for (int kk = 0; kk < 4; kk++) {
            bf16x8 av = *(const bf16x8*)(hr + kk * 32);
            acc = __builtin_amdgcn_mfma_f32_16x16x32_bf16(bw[kk], av, acc, 0, 0, 0);
        }
        if (node < Nn) {
            int f0 = wv * 16 + q * 4;
            if (f0 < NC) {
                ushort4 o;
                o.x = f2bf(acc[0]); o.y = f2bf(acc[1]);
                o.z = f2bf(acc[2]); o.w = f2bf(acc[3]);
                *(ushort4*)(h2b + (size_t)node * 64 + f0) = o;
            } else {
                int cc = f0 - NC;
                float4 b4 = *(const float4*)(r2b + cc);
                float4 o;
                o.x = acc[0] + b4.x; o.y = acc[1] + b4.y;
                o.z = acc[2] + b4.z; o.w = acc[3] + b4.w;
                *(float4*)(outp + (size_t)node * NC + cc) = o;
            }
        }
    }
}

// ---------------- layer 2 gather-aggregate: shuffle-free + log_softmax ----------------

__global__ __launch_bounds__(256) void agg2_kernel(
        const int* __restrict__ rs, const int* __restrict__ csr,
        const float* __restrict__ as, const float* __restrict__ ad,
        const unsigned short* __restrict__ h2b, const float* __restrict__ b2,
        float* __restrict__ outp) {
    int lane = threadIdx.x & 63, wv = threadIdx.x >> 6;
    int n = blockIdx.x * 4 + wv;
    if (n >= Nn) return;
    int row = rs[n], end = rs[n + 1];
    float adn = ad[n];
    int slot = lane >> 3, h = lane & 7;
    const unsigned short* hcol = h2b + h * 8;

    float a[8];
    #pragma unroll
    for (int i = 0; i < 8; i++) a[i] = 0.f;
    float den = 0.f;

    bool v = slot < end - row;
    int sl = v ? csr[row + slot] : 0;
    for (int j = row; j < end; j += 8) {
        bool cv = v;
        int cur = sl;
        int jn = j + 8;
        if (jn < end) {
            v = slot < end - jn;
            sl = v ? csr[jn + slot] : 0;
        }
        float lg = as[cur] + adn;
        lg = fmaxf(lg, SLOPE * lg);
        float e = cv ? __expf(lg) : 0.f;
        den += e;
        u32x4 u0 = *(const u32x4*)(hcol + (size_t)cur * 64);
        #pragma unroll
        for (int k = 0; k < 4; k++) {
            unsigned u = u0[k];
            a[2 * k]     += e * __uint_as_float(u << 16);
            a[2 * k + 1] += e * __uint_as_float(u & 0xffff0000u);
        }
    }

    den += __shfl_xor(den, 8, 64);
    den += __shfl_xor(den, 16, 64);
    den += __shfl_xor(den, 32, 64);
    float inv = 1.f / den;

    int l3 = (lane >> 3) & 1, l4 = (lane >> 4) & 1, l5 = (lane >> 5) & 1;
    float c4[4];
    #pragma unroll
    for (int i = 0; i < 4; i++) {
        float mine = l3 ? a[i + 4] : a[i];
        float send = l3 ? a[i] : a[i + 4];
        c4[i] = mine + __shfl_xor(send, 8, 64);
    }
    float c2[2];
    #pragma unroll
    for (int i = 0; i < 2; i++) {
        float mine = l4 ? c4[i + 2] : c4[i];
        float send = l4 ? c4[i] : c4[i + 2];
        c2[i] = mine + __shfl_xor(send, 16, 64);
    }
    float mine = l5 ? c2[1] : c2[0];
    float send = l5 ? c2[0] : c2[1];
    float av = mine + __shfl_xor(send, 32, 64);
    int c = h * 8 + l3 * 4 + l4 * 2 + l5;
    bool act = c < NC;

    float v0 = -3.4e38f;
    if (act) v0 = av * inv + b2[c] + outp[(size_t)n * NC + c];
    float mm = v0;
    #pragma unroll
    for (int st = 32; st >= 1; st >>= 1) mm = fmaxf(mm, __shfl_xor(mm, st, 64));
    float ex = act ? __expf(v0 - mm) : 0.f;
    float ss = ex;
    #pragma unroll
    for (int st = 32; st >= 1; st >>= 1) ss += __shfl_xor(ss, st, 64);
    if (act) {
        float lg = mm + logf(ss);
        outp[(size_t)n * NC + c] = v0 - lg;
    }
}

// ---------------- host ----------------

extern "C" void kernel_launch(void* const* d_in, const int* in_sizes, int n_in,
                              void* d_out, int out_size, void* d_ws, size_t ws_size,
                              hipStream_t stream) {
    const float* x      = (const float*)d_in[0];
    const int*   ei     = (const int*)d_in[1];
    const float* W1     = (const float*)d_in[2];
    const float* att_s1 = (const float*)d_in[3];
    const float* att_d1 = (const float*)d_in[4];
    const float* bias1  = (const float*)d_in[5];
    const float* W2     = (const float*)d_in[6];
    const float* att_s2 = (const float*)d_in[7];
    const float* att_d2 = (const float*)d_in[8];
    const float* bias2  = (const float*)d_in[9];
    const float* r1W    = (const float*)d_in[10];
    const float* r1b    = (const float*)d_in[11];
    const float* r2W    = (const float*)d_in[12];
    const float* r2b    = (const float*)d_in[13];
    float* out = (float*)d_out;

    float* ws   = (float*)d_ws;
    float* as1  = ws;                            // N*8
    float* ad1  = as1 + (size_t)Nn * 8;          // N*8
    float* as2  = ad1 + (size_t)Nn * 8;          // N
    float* ad2  = as2 + Nn;                      // N
    float* wts  = ad2 + Nn;                      // 128
    float* wtd  = wts + 128;                     // 128
    unsigned short* hbufb = (unsigned short*)(wtd + 128);  // N*128 bf16 (res1)
    unsigned short* h1b = hbufb + (size_t)Nn * 128;        // N*128 bf16
    unsigned short* hb  = h1b + (size_t)Nn * 128;          // N*128 bf16 (post-agg1 h)
    unsigned short* Wb1t = hb + (size_t)Nn * 128;          // 256*128 bf16
    unsigned short* Wb2t = Wb1t + 256 * 128;               // 80*128 bf16
    uintptr_t pal = ((uintptr_t)(Wb2t + 80 * 128) + 15) & ~(uintptr_t)15;
    long long* pairs = (long long*)pal;          // NBUK*CAPB pairs (dead after partB)
    unsigned short* h2b = (unsigned short*)pal;  // N*64 bf16, ALIASES pairs (used after partB)
    int* rs      = (int*)(pairs + (size_t)NBUK * CAPB);  // N+1
    int* bukcnt  = rs + Nn + 1;                  // NBUK
    int* csr     = bukcnt + NBUK;                // EP

    // ---- weight prep + bukcnt zero + rs[Nn] ----
    castW_kernel<<<(256 * 128 + 80 * 128 + 256 + NBUK + 1 + 255) / 256, 256, 0, stream>>>(
        W1, r1W, W2, r2W, att_s2, att_d2, Wb1t, Wb2t, wts, wtd, bukcnt, rs);

    // ---- partA || gemm1 (1024-thread blocks, independent work overlapped) ----
    fused1_kernel<<<NBA + G1B, 1024, 0, stream>>>(x, Wb1t, r1b, att_s1, att_d1,
                                                  h1b, hbufb, as1, ad1,
                                                  ei, bukcnt, pairs);

    // ---- CSR finalize ----
    partB_kernel<<<NBUK, 512, 0, stream>>>(pairs, bukcnt, rs, csr);

    // ---- layer 1 aggregate ----
    agg1_kernel<<<(Nn + 3) / 4, 256, 0, stream>>>(rs, csr, as1, ad1, h1b, bias1,
                                                  hbufb, hb, wts, wtd, as2, ad2);

    // ---- layer 2 ----
    gemm2_kernel<<<(Nn + 63) / 64, 320, 0, stream>>>(hb, Wb2t, r2b, h2b, out);
    agg2_kernel<<<(Nn + 3) / 4, 256, 0, stream>>>(rs, csr, as2, ad2, h2b, bias2, out);
}

// Round 11
// 354.755 us; speedup vs baseline: 1.0284x; 1.0284x over previous
//
#include <hip/hip_runtime.h>
#include <math.h>

#define Nn 100000
#define Ee 1600000
#define EP 1700000   /* Ee + Nn self loops */
#define NC 40
#define SLOPE 0.2f
#define GSZ 256      /* nodes per bucket */
#define NBUK 391     /* ceil(Nn/GSZ) */
#define CAPB 8192    /* padded capacity per bucket */
#define CHA 8192     /* edges per partition block */
#define NBA ((EP + CHA - 1) / CHA)
#define G1B ((Nn + 63) / 64)   /* 64 nodes per gemm block */
#define XCB 6250     /* castW blocks converting x: 100000*128/8/256 */

typedef short bf16x8 __attribute__((ext_vector_type(8)));
typedef unsigned short u16x8 __attribute__((ext_vector_type(8)));
typedef float f32x4 __attribute__((ext_vector_type(4)));
typedef unsigned int u32x4 __attribute__((ext_vector_type(4)));

// ---------- bf16 helpers ----------

__device__ __forceinline__ unsigned short f2bf(float f) {
    unsigned u = __float_as_uint(f);
    unsigned r = u + 0x7FFFu + ((u >> 16) & 1u);
    return (unsigned short)(r >> 16);
}
__device__ __forceinline__ float bf2f(unsigned short u) {
    return __uint_as_float(((unsigned)u) << 16);
}

// ---------------- x->bf16 + weight cast/transpose + w~ vectors + bukcnt zero + rs[Nn] ----------------

__global__ void castW_kernel(const float* __restrict__ x, unsigned short* __restrict__ xb,
                             const float* __restrict__ W1, const float* __restrict__ r1W,
                             const float* __restrict__ W2, const float* __restrict__ r2W,
                             const float* __restrict__ att_s2, const float* __restrict__ att_d2,
                             unsigned short* __restrict__ Wb1t, unsigned short* __restrict__ Wb2t,
                             float* __restrict__ wts, float* __restrict__ wtd,
                             int* __restrict__ bukcnt, int* __restrict__ rs) {
    if (blockIdx.x < XCB) {
        // convert x (100000 x 128 f32) to bf16, 8 elems/thread, fully coalesced
        size_t i = ((size_t)blockIdx.x * 256 + threadIdx.x) * 8;
        float4 a0 = *(const float4*)(x + i);
        float4 a1 = *(const float4*)(x + i + 4);
        u16x8 o;
        o[0] = f2bf(a0.x); o[1] = f2bf(a0.y); o[2] = f2bf(a0.z); o[3] = f2bf(a0.w);
        o[4] = f2bf(a1.x); o[5] = f2bf(a1.y); o[6] = f2bf(a1.z); o[7] = f2bf(a1.w);
        *(u16x8*)(xb + i) = o;
        return;
    }
    int tid = (blockIdx.x - XCB) * 256 + threadIdx.x;
    if (tid < 256 * 128) {
        int col = tid >> 7, k = tid & 127;
        float v = (col < 128) ? W1[k * 128 + col] : r1W[k * 128 + (col - 128)];
        Wb1t[col * 128 + k] = f2bf(v);
    } else if (tid < 256 * 128 + 80 * 128) {
        int t2 = tid - 256 * 128;
        int col = t2 >> 7, k = t2 & 127;
        float v = (col < NC) ? W2[k * NC + col] : r2W[k * NC + (col - NC)];
        Wb2t[col * 128 + k] = f2bf(v);
    } else {
        int t3 = tid - 256 * 128 - 80 * 128;
        if (t3 < 128) {
            float s = 0.f;
            for (int c = 0; c < NC; c++) s += W2[t3 * NC + c] * att_s2[c];
            wts[t3] = s;
        } else if (t3 < 256) {
            int k = t3 - 128;
            float s = 0.f;
            for (int c = 0; c < NC; c++) s += W2[k * NC + c] * att_d2[c];
            wtd[k] = s;
        } else {
            int t4 = t3 - 256;
            if (t4 < NBUK) bukcnt[t4] = 0;
            else if (t4 == NBUK) rs[Nn] = EP;
        }
    }
}

// ---------------- fused: partA (CSR bucket scatter) || gemm1 (64 nodes/block, bf16 x, reg weights) ----------------

__global__ __launch_bounds__(256) void fused1_kernel(
        const unsigned short* __restrict__ xb, const unsigned short* __restrict__ Wb1t,
        const float* __restrict__ r1b,
        const float* __restrict__ att_s, const float* __restrict__ att_d,
        unsigned short* __restrict__ h1b, unsigned short* __restrict__ hbufb,
        float* __restrict__ as1, float* __restrict__ ad1,
        const int* __restrict__ ei, int* __restrict__ bukcnt,
        long long* __restrict__ pairs) {
    __shared__ int smem[NBUK * 2];
    if (blockIdx.x < NBA) {
        // ---- partA body (load-batched) ----
        int* cntA = smem;
        int* resA = smem + NBUK;
        int t = threadIdx.x;
        for (int i = t; i < NBUK; i += 256) cntA[i] = 0;
        __syncthreads();
        int e0 = blockIdx.x * CHA;
        int cnt = EP - e0; if (cnt > CHA) cnt = CHA;   // always a multiple of 4

        int4 dd[8];
        #pragma unroll
        for (int p = 0; p < 8; p++) {
            int k = t * 4 + p * 1024;
            int e = e0 + k;
            if (k < cnt) {
                if (e + 3 < Ee) {
                    dd[p] = *(const int4*)(ei + Ee + e);
                } else {
                    dd[p].x = (e     < Ee) ? ei[Ee + e]     : e     - Ee;
                    dd[p].y = (e + 1 < Ee) ? ei[Ee + e + 1] : e + 1 - Ee;
                    dd[p].z = (e + 2 < Ee) ? ei[Ee + e + 2] : e + 2 - Ee;
                    dd[p].w = (e + 3 < Ee) ? ei[Ee + e + 3] : e + 3 - Ee;
                }
            } else {
                dd[p] = (int4){-1, -1, -1, -1};
            }
        }
        #pragma unroll
        for (int p = 0; p < 8; p++) {
            if (dd[p].x >= 0) {
                atomicAdd(&cntA[dd[p].x >> 8], 1);
                atomicAdd(&cntA[dd[p].y >> 8], 1);
                atomicAdd(&cntA[dd[p].z >> 8], 1);
                atomicAdd(&cntA[dd[p].w >> 8], 1);
            }
        }
        __syncthreads();
        for (int b = t; b < NBUK; b += 256) {
            int c = cntA[b];
            resA[b] = c ? atomicAdd(&bukcnt[b], c) : 0;
            cntA[b] = 0;
        }
        __syncthreads();
        #pragma unroll
        for (int hf = 0; hf < 2; hf++) {
            int4 ss[4];
            #pragma unroll
            for (int p = 0; p < 4; p++) {
                int k = t * 4 + (hf * 4 + p) * 1024;
                int e = e0 + k;
                if (k < cnt) {
                    if (e + 3 < Ee) {
                        ss[p] = *(const int4*)(ei + e);
                    } else {
                        ss[p].x = (e     < Ee) ? ei[e]     : e     - Ee;
                        ss[p].y = (e + 1 < Ee) ? ei[e + 1] : e + 1 - Ee;
                        ss[p].z = (e + 2 < Ee) ? ei[e + 2] : e + 2 - Ee;
                        ss[p].w = (e + 3 < Ee) ? ei[e + 3] : e + 3 - Ee;
                    }
                }
            }
            #pragma unroll
            for (int p = 0; p < 4; p++) {
                int4 d = dd[hf * 4 + p];
                if (d.x >= 0) {
                    int b0 = d.x >> 8; int r0 = atomicAdd(&cntA[b0], 1);
                    pairs[(size_t)b0 * CAPB + resA[b0] + r0] = ((long long)d.x << 32) | (unsigned)ss[p].x;
                    int b1 = d.y >> 8; int r1 = atomicAdd(&cntA[b1], 1);
                    pairs[(size_t)b1 * CAPB + resA[b1] + r1] = ((long long)d.y << 32) | (unsigned)ss[p].y;
                    int b2 = d.z >> 8; int r2 = atomicAdd(&cntA[b2], 1);
                    pairs[(size_t)b2 * CAPB + resA[b2] + r2] = ((long long)d.z << 32) | (unsigned)ss[p].z;
                    int b3 = d.w >> 8; int r3 = atomicAdd(&cntA[b3], 1);
                    pairs[(size_t)b3 * CAPB + resA[b3] + r3] = ((long long)d.w << 32) | (unsigned)ss[p].w;
                }
            }
        }
    } else {
        // ---- gemm1 body: 64 nodes/block, bf16 x loads (no conversion), reg weights ----
        int lane = threadIdx.x & 63, wv = threadIdx.x >> 6;
        int m = lane & 15, q = lane >> 4;
        int nb = (blockIdx.x - NBA) * 64;

        bf16x8 bw[4][4];
        #pragma unroll
        for (int t = 0; t < 4; t++) {
            const unsigned short* bp = Wb1t + (size_t)((wv * 4 + t) * 16 + m) * 128 + q * 8;
            #pragma unroll
            for (int kk = 0; kk < 4; kk++)
                bw[t][kk] = *(const bf16x8*)(bp + kk * 32);
        }

        #pragma unroll
        for (int ng = 0; ng < 4; ng++) {
            int node = nb + ng * 16 + m;
            int nld = node < Nn ? node : Nn - 1;

            bf16x8 af[4];
            const unsigned short* xr = xb + (size_t)nld * 128 + q * 8;
            #pragma unroll
            for (int kk = 0; kk < 4; kk++)
                af[kk] = *(const bf16x8*)(xr + kk * 32);

            f32x4 acc[4];
            #pragma unroll
            for (int t = 0; t < 4; t++) acc[t] = (f32x4){0.f, 0.f, 0.f, 0.f};
            #pragma unroll
            for (int t = 0; t < 4; t++) {
                #pragma unroll
                for (int kk = 0; kk < 4; kk++)
                    acc[t] = __builtin_amdgcn_mfma_f32_16x16x32_bf16(bw[t][kk], af[kk], acc[t], 0, 0, 0);
            }

            if (node < Nn) {
                if (wv < 2) {
                    float psum[4], pdum[4];
                    #pragma unroll
                    for (int t = 0; t < 4; t++) {
                        int c0 = (wv * 4 + t) * 16 + q * 4;
                        ushort4 o;
                        o.x = f2bf(acc[t][0]); o.y = f2bf(acc[t][1]);
                        o.z = f2bf(acc[t][2]); o.w = f2bf(acc[t][3]);
                        *(ushort4*)(h1b + (size_t)node * 128 + c0) = o;
                        float4 s4 = *(const float4*)(att_s + c0);
                        float4 d4 = *(const float4*)(att_d + c0);
                        float ps = acc[t][0] * s4.x + acc[t][1] * s4.y + acc[t][2] * s4.z + acc[t][3] * s4.w;
                        float pd = acc[t][0] * d4.x + acc[t][1] * d4.y + acc[t][2] * d4.z + acc[t][3] * d4.w;
                        ps += __shfl_xor(ps, 16, 64); ps += __shfl_xor(ps, 32, 64);
                        pd += __shfl_xor(pd, 16, 64); pd += __shfl_xor(pd, 32, 64);
                        psum[t] = ps; pdum[t] = pd;
                    }
                    if (q == 0) {
                        float4 o; o.x = psum[0]; o.y = psum[1]; o.z = psum[2]; o.w = psum[3];
                        *(float4*)(as1 + (size_t)node * 8 + wv * 4) = o;
                    } else if (q == 1) {
                        float4 o; o.x = pdum[0]; o.y = pdum[1]; o.z = pdum[2]; o.w = pdum[3];
                        *(float4*)(ad1 + (size_t)node * 8 + wv * 4) = o;
                    }
                } else {
                    #pragma unroll
                    for (int t = 0; t < 4; t++) {
                        int cc0 = ((wv - 2) * 4 + t) * 16 + q * 4;
                        float4 b4 = *(const float4*)(r1b + cc0);
                        ushort4 o;
                        o.x = f2bf(acc[t][0] + b4.x); o.y = f2bf(acc[t][1] + b4.y);
                        o.z = f2bf(acc[t][2] + b4.z); o.w = f2bf(acc[t][3] + b4.w);
                        *(ushort4*)(hbufb + (size_t)node * 128 + cc0) = o;
                    }
                }
            }
        }
    }
}

// ---------------- phase B: 512 threads, inline bucket prefix + per-node rs + CSR scatter ----------------

__global__ __launch_bounds__(512) void partB_kernel(const long long* __restrict__ pairs,
                                                    const int* __restrict__ bukcnt,
                                                    int* __restrict__ rs,
                                                    int* __restrict__ csr) {
    __shared__ int lcnt[GSZ];
    __shared__ int lbase[GSZ];
    __shared__ int bsum[8];
    int b = blockIdx.x;
    int t = threadIdx.x;
    int node0 = b * GSZ;
    int nodes = Nn - node0; if (nodes > GSZ) nodes = GSZ;
    int acc = 0;
    for (int i = t; i < b; i += 512) acc += bukcnt[i];
    #pragma unroll
    for (int st = 1; st < 64; st <<= 1) acc += __shfl_xor(acc, st, 64);
    if ((t & 63) == 0) bsum[t >> 6] = acc;
    if (t < GSZ) lcnt[t] = 0;
    __syncthreads();
    int bb = bsum[0] + bsum[1] + bsum[2] + bsum[3]
           + bsum[4] + bsum[5] + bsum[6] + bsum[7];
    int lo = b * CAPB;
    int hi = lo + bukcnt[b];
    for (int j = lo + t; j < hi; j += 512) {
        int li = (int)(pairs[j] >> 32) - node0;
        atomicAdd(&lcnt[li], 1);
    }
    __syncthreads();
    int c = (t < GSZ) ? lcnt[t] : 0;
    if (t < GSZ) lbase[t] = c;
    __syncthreads();
    #pragma unroll
    for (int off = 1; off < 256; off <<= 1) {
        int u = (t >= off && t < GSZ) ? lbase[t - off] : 0;
        __syncthreads();
        if (t < GSZ) lbase[t] += u;
        __syncthreads();
    }
    if (t < GSZ) {
        int myBase = bb + lbase[t] - c;
        if (t < nodes) rs[node0 + t] = myBase;
        lbase[t] = myBase;
        lcnt[t] = 0;
    }
    __syncthreads();
    for (int j = lo + t; j < hi; j += 512) {
        long long p = pairs[j];
        int li = (int)(p >> 32) - node0;
        int r = atomicAdd(&lcnt[li], 1);
        csr[lbase[li] + r] = (int)(p & 0xffffffffLL);
    }
}

// ---------------- layer 1 gather-aggregate: shuffle-free + csr/as software pipeline ----------------

__global__ __launch_bounds__(256) void agg1_kernel(
        const int* __restrict__ rs, const int* __restrict__ csr,
        const float* __restrict__ as, const float* __restrict__ ad,
        const unsigned short* __restrict__ h1b, const float* __restrict__ bias,
        const unsigned short* __restrict__ hbufb, unsigned short* __restrict__ hb,
        const float* __restrict__ wts, const float* __restrict__ wtd,
        float* __restrict__ as2, float* __restrict__ ad2) {
    int lane = threadIdx.x & 63, wv = threadIdx.x >> 6;
    int n = blockIdx.x * 4 + wv;
    if (n >= Nn) return;
    int row = rs[n], end = rs[n + 1];
    int slot = lane >> 3;
    int h = lane & 7;
    float adh = ad[n * 8 + h];
    const unsigned short* hcol = h1b + h * 16;

    float a[16];
    #pragma unroll
    for (int i = 0; i < 16; i++) a[i] = 0.f;
    float den = 0.f;

    // software-pipelined: csr AND as-gather for the current chunk load one iteration ahead
    bool v = slot < end - row;
    int sl = v ? csr[row + slot] : 0;
    float asv = as[sl * 8 + h];
    for (int j = row; j < end; j += 8) {
        bool cv = v;
        int cur = sl;
        float casv = asv;
        int jn = j + 8;
        if (jn < end) {
            v = slot < end - jn;
            sl = v ? csr[jn + slot] : 0;
            asv = as[sl * 8 + h];
        }
        float lg = casv + adh;
        lg = fmaxf(lg, SLOPE * lg);
        float e = cv ? __expf(lg) : 0.f;
        den += e;
        const unsigned short* p = hcol + (size_t)cur * 128;
        u32x4 u0 = *(const u32x4*)(p);
        u32x4 u1 = *(const u32x4*)(p + 8);
        #pragma unroll
        for (int k = 0; k < 4; k++) {
            unsigned u = u0[k];
            a[2 * k]     += e * __uint_as_float(u << 16);
            a[2 * k + 1] += e * __uint_as_float(u & 0xffff0000u);
            unsigned w = u1[k];
            a[8 + 2 * k]     += e * __uint_as_float(w << 16);
            a[8 + 2 * k + 1] += e * __uint_as_float(w & 0xffff0000u);
        }
    }

    den += __shfl_xor(den, 8, 64);
    den += __shfl_xor(den, 16, 64);
    den += __shfl_xor(den, 32, 64);
    float inv = 1.f / den;

    int l3 = (lane >> 3) & 1, l4 = (lane >> 4) & 1, l5 = (lane >> 5) & 1;
    float b8[8];
    #pragma unroll
    for (int i = 0; i < 8; i++) {
        float mine = l3 ? a[i + 8] : a[i];
        float send = l3 ? a[i] : a[i + 8];
        b8[i] = mine + __shfl_xor(send, 8, 64);
    }
    float b4[4];
    #pragma unroll
    for (int i = 0; i < 4; i++) {
        float mine = l4 ? b8[i + 4] : b8[i];
        float send = l4 ? b8[i] : b8[i + 4];
        b4[i] = mine + __shfl_xor(send, 16, 64);
    }
    float c2[2];
    #pragma unroll
    for (int i = 0; i < 2; i++) {
        float mine = l5 ? b4[i + 2] : b4[i];
        float send = l5 ? b4[i] : b4[i + 2];
        c2[i] = mine + __shfl_xor(send, 32, 64);
    }
    int c0 = h * 16 + l3 * 8 + l4 * 4 + l5 * 2;

    float g0 = c2[0] * inv + bias[c0];
    float g1 = c2[1] * inv + bias[c0 + 1];
    unsigned rr = *(const unsigned*)(hbufb + (size_t)n * 128 + c0);
    g0 = (g0 > 0.f ? g0 : __expf(g0) - 1.f) + __uint_as_float(rr << 16);
    g1 = (g1 > 0.f ? g1 : __expf(g1) - 1.f) + __uint_as_float(rr & 0xffff0000u);
    unsigned o = ((unsigned)f2bf(g0)) | (((unsigned)f2bf(g1)) << 16);
    *(unsigned*)(hb + (size_t)n * 128 + c0) = o;
    float2 wsv = *(const float2*)(wts + c0);
    float2 wdv = *(const float2*)(wtd + c0);
    float ps = g0 * wsv.x + g1 * wsv.y;
    float pd = g0 * wdv.x + g1 * wdv.y;
    #pragma unroll
    for (int st = 32; st >= 1; st >>= 1) {
        ps += __shfl_xor(ps, st, 64);
        pd += __shfl_xor(pd, st, 64);
    }
    if (lane == 0) { as2[n] = ps; ad2[n] = pd; }
}

// ---------------- layer 2 GEMM: 64 nodes/block, reg weights, h2b (stride 64) + residual-out ----------------

__global__ __launch_bounds__(320) void gemm2_kernel(
        const unsigned short* __restrict__ hb, const unsigned short* __restrict__ Wb2t,
        const float* __restrict__ r2b,
        unsigned short* __restrict__ h2b, float* __restrict__ outp) {
    int lane = threadIdx.x & 63, wv = threadIdx.x >> 6;   // wv 0..4
    int m = lane & 15, q = lane >> 4;
    int nb = blockIdx.x * 64;

    bf16x8 bw[4];
    const unsigned short* bp = Wb2t + (size_t)(wv * 16 + m) * 128 + q * 8;
    #pragma unroll
    for (int kk = 0; kk < 4; kk++) bw[kk] = *(const bf16x8*)(bp + kk * 32);

    #pragma unroll
    for (int ng = 0; ng < 4; ng++) {
        int node = nb + ng * 16 + m;
        int nld = node < Nn ? node : Nn - 1;
        const unsigned short* hr = hb + (size_t)nld * 128 + q * 8;
        f32x4 acc = (f32x4){0.f, 0.f, 0.f, 0.f};
        #pragma unroll
        for (int kk = 0; kk < 4; kk++) {
            bf16x8 av = *(const bf16x8*)(hr + kk * 32);
            acc = __builtin_amdgcn_mfma_f32_16x16x32_bf16(bw[kk], av, acc, 0, 0, 0);
        }
        if (node < Nn) {
            int f0 = wv * 16 + q * 4;
            if (f0 < NC) {
                ushort4 o;
                o.x = f2bf(acc[0]); o.y = f2bf(acc[1]);
                o.z = f2bf(acc[2]); o.w = f2bf(acc[3]);
                *(ushort4*)(h2b + (size_t)node * 64 + f0) = o;
            } else {
                int cc = f0 - NC;
                float4 b4 = *(const float4*)(r2b + cc);
                float4 o;
                o.x = acc[0] + b4.x; o.y = acc[1] + b4.y;
                o.z = acc[2] + b4.z; o.w = acc[3] + b4.w;
                *(float4*)(outp + (size_t)node * NC + cc) = o;
            }
        }
    }
}

// ---------------- layer 2 gather-aggregate: shuffle-free + csr/as pipeline + log_softmax ----------------

__global__ __launch_bounds__(256) void agg2_kernel(
        const int* __restrict__ rs, const int* __restrict__ csr,
        const float* __restrict__ as, const float* __restrict__ ad,
        const unsigned short* __restrict__ h2b, const float* __restrict__ b2,
        float* __restrict__ outp) {
    int lane = threadIdx.x & 63, wv = threadIdx.x >> 6;
    int n = blockIdx.x * 4 + wv;
    if (n >= Nn) return;
    int row = rs[n], end = rs[n + 1];
    float adn = ad[n];
    int slot = lane >> 3, h = lane & 7;
    const unsigned short* hcol = h2b + h * 8;

    float a[8];
    #pragma unroll
    for (int i = 0; i < 8; i++) a[i] = 0.f;
    float den = 0.f;

    bool v = slot < end - row;
    int sl = v ? csr[row + slot] : 0;
    float asv = as[sl];
    for (int j = row; j < end; j += 8) {
        bool cv = v;
        int cur = sl;
        float casv = asv;
        int jn = j + 8;
        if (jn < end) {
            v = slot < end - jn;
            sl = v ? csr[jn + slot] : 0;
            asv = as[sl];
        }
        float lg = casv + adn;
        lg = fmaxf(lg, SLOPE * lg);
        float e = cv ? __expf(lg) : 0.f;
        den += e;
        u32x4 u0 = *(const u32x4*)(hcol + (size_t)cur * 64);
        #pragma unroll
        for (int k = 0; k < 4; k++) {
            unsigned u = u0[k];
            a[2 * k]     += e * __uint_as_float(u << 16);
            a[2 * k + 1] += e * __uint_as_float(u & 0xffff0000u);
        }
    }

    den += __shfl_xor(den, 8, 64);
    den += __shfl_xor(den, 16, 64);
    den += __shfl_xor(den, 32, 64);
    float inv = 1.f / den;

    int l3 = (lane >> 3) & 1, l4 = (lane >> 4) & 1, l5 = (lane >> 5) & 1;
    float c4[4];
    #pragma unroll
    for (int i = 0; i < 4; i++) {
        float mine = l3 ? a[i + 4] : a[i];
        float send = l3 ? a[i] : a[i + 4];
        c4[i] = mine + __shfl_xor(send, 8, 64);
    }
    float c2[2];
    #pragma unroll
    for (int i = 0; i < 2; i++) {
        float mine = l4 ? c4[i + 2] : c4[i];
        float send = l4 ? c4[i] : c4[i + 2];
        c2[i] = mine + __shfl_xor(send, 16, 64);
    }
    float mine = l5 ? c2[1] : c2[0];
    float send = l5 ? c2[0] : c2[1];
    float av = mine + __shfl_xor(send, 32, 64);
    int c = h * 8 + l3 * 4 + l4 * 2 + l5;
    bool act = c < NC;

    float v0 = -3.4e38f;
    if (act) v0 = av * inv + b2[c] + outp[(size_t)n * NC + c];
    float mm = v0;
    #pragma unroll
    for (int st = 32; st >= 1; st >>= 1) mm = fmaxf(mm, __shfl_xor(mm, st, 64));
    float ex = act ? __expf(v0 - mm) : 0.f;
    float ss = ex;
    #pragma unroll
    for (int st = 32; st >= 1; st >>= 1) ss += __shfl_xor(ss, st, 64);
    if (act) {
        float lg = mm + logf(ss);
        outp[(size_t)n * NC + c] = v0 - lg;
    }
}

// ---------------- host ----------------

extern "C" void kernel_launch(void* const* d_in, const int* in_sizes, int n_in,
                              void* d_out, int out_size, void* d_ws, size_t ws_size,
                              hipStream_t stream) {
    const float* x      = (const float*)d_in[0];
    const int*   ei     = (const int*)d_in[1];
    const float* W1     = (const float*)d_in[2];
    const float* att_s1 = (const float*)d_in[3];
    const float* att_d1 = (const float*)d_in[4];
    const float* bias1  = (const float*)d_in[5];
    const float* W2     = (const float*)d_in[6];
    const float* att_s2 = (const float*)d_in[7];
    const float* att_d2 = (const float*)d_in[8];
    const float* bias2  = (const float*)d_in[9];
    const float* r1W    = (const float*)d_in[10];
    const float* r1b    = (const float*)d_in[11];
    const float* r2W    = (const float*)d_in[12];
    const float* r2b    = (const float*)d_in[13];
    float* out = (float*)d_out;

    float* ws   = (float*)d_ws;
    float* as1  = ws;                            // N*8
    float* ad1  = as1 + (size_t)Nn * 8;          // N*8
    float* as2  = ad1 + (size_t)Nn * 8;          // N
    float* ad2  = as2 + Nn;                      // N
    float* wts  = ad2 + Nn;                      // 128
    float* wtd  = wts + 128;                     // 128
    unsigned short* hbufb = (unsigned short*)(wtd + 128);  // N*128 bf16 (res1)
    unsigned short* h1b = hbufb + (size_t)Nn * 128;        // N*128 bf16
    unsigned short* hb  = h1b + (size_t)Nn * 128;          // N*128 bf16 (post-agg1 h)
    unsigned short* Wb1t = hb + (size_t)Nn * 128;          // 256*128 bf16
    unsigned short* Wb2t = Wb1t + 256 * 128;               // 80*128 bf16
    unsigned short* xb   = Wb2t + 80 * 128;                // N*128 bf16 (pre-cast x)
    uintptr_t pal = ((uintptr_t)(xb + (size_t)Nn * 128) + 15) & ~(uintptr_t)15;
    long long* pairs = (long long*)pal;          // NBUK*CAPB pairs (dead after partB)
    unsigned short* h2b = (unsigned short*)pal;  // N*64 bf16, ALIASES pairs (used after partB)
    int* rs      = (int*)(pairs + (size_t)NBUK * CAPB);  // N+1
    int* bukcnt  = rs + Nn + 1;                  // NBUK
    int* csr     = bukcnt + NBUK;                // EP

    // ---- x->bf16 + weight prep + bukcnt zero + rs[Nn] ----
    castW_kernel<<<XCB + (256 * 128 + 80 * 128 + 256 + NBUK + 1 + 255) / 256, 256, 0, stream>>>(
        x, xb, W1, r1W, W2, r2W, att_s2, att_d2, Wb1t, Wb2t, wts, wtd, bukcnt, rs);

    // ---- partA || gemm1 (independent, overlapped) ----
    fused1_kernel<<<NBA + G1B, 256, 0, stream>>>(xb, Wb1t, r1b, att_s1, att_d1,
                                                 h1b, hbufb, as1, ad1,
                                                 ei, bukcnt, pairs);

    // ---- CSR finalize ----
    partB_kernel<<<NBUK, 512, 0, stream>>>(pairs, bukcnt, rs, csr);

    // ---- layer 1 aggregate ----
    agg1_kernel<<<(Nn + 3) / 4, 256, 0, stream>>>(rs, csr, as1, ad1, h1b, bias1,
                                                  hbufb, hb, wts, wtd, as2, ad2);

    // ---- layer 2 ----
    gemm2_kernel<<<(Nn + 63) / 64, 320, 0, stream>>>(hb, Wb2t, r2b, h2b, out);
    agg2_kernel<<<(Nn + 3) / 4, 256, 0, stream>>>(rs, csr, as2, ad2, h2b, bias2, out);
}

// Round 12
// 353.002 us; speedup vs baseline: 1.0335x; 1.0050x over previous
//
#include <hip/hip_runtime.h>
#include <math.h>

#define Nn 100000
#define Ee 1600000
#define EP 1700000   /* Ee + Nn self loops */
#define NC 40
#define SLOPE 0.2f
#define GSZ 256      /* nodes per bucket */
#define NBUK 391     /* ceil(Nn/GSZ) */
#define CAPB 8192    /* padded capacity per bucket */
#define CHA 8192     /* edges per partition block */
#define NBA ((EP + CHA - 1) / CHA)
#define G1B ((Nn + 63) / 64)   /* 64 nodes per gemm block */
#define XCB 6250     /* castW blocks converting x: 100000*128/8/256 */

typedef short bf16x8 __attribute__((ext_vector_type(8)));
typedef unsigned short u16x8 __attribute__((ext_vector_type(8)));
typedef float f32x4 __attribute__((ext_vector_type(4)));
typedef unsigned int u32x4 __attribute__((ext_vector_type(4)));

// ---------- bf16 helpers ----------

__device__ __forceinline__ unsigned short f2bf(float f) {
    unsigned u = __float_as_uint(f);
    unsigned r = u + 0x7FFFu + ((u >> 16) & 1u);
    return (unsigned short)(r >> 16);
}
__device__ __forceinline__ float bf2f(unsigned short u) {
    return __uint_as_float(((unsigned)u) << 16);
}

// ---------------- x->bf16 + weight cast/transpose + w~ vectors (f32 + bf16) + bukcnt zero + rs[Nn] ----------------

__global__ void castW_kernel(const float* __restrict__ x, unsigned short* __restrict__ xb,
                             const float* __restrict__ W1, const float* __restrict__ r1W,
                             const float* __restrict__ W2, const float* __restrict__ r2W,
                             const float* __restrict__ att_s2, const float* __restrict__ att_d2,
                             unsigned short* __restrict__ Wb1t, unsigned short* __restrict__ Wb2t,
                             float* __restrict__ wts, float* __restrict__ wtd,
                             unsigned short* __restrict__ wtsb, unsigned short* __restrict__ wtdb,
                             int* __restrict__ bukcnt, int* __restrict__ rs) {
    if (blockIdx.x < XCB) {
        // convert x (100000 x 128 f32) to bf16, 8 elems/thread, fully coalesced
        size_t i = ((size_t)blockIdx.x * 256 + threadIdx.x) * 8;
        float4 a0 = *(const float4*)(x + i);
        float4 a1 = *(const float4*)(x + i + 4);
        u16x8 o;
        o[0] = f2bf(a0.x); o[1] = f2bf(a0.y); o[2] = f2bf(a0.z); o[3] = f2bf(a0.w);
        o[4] = f2bf(a1.x); o[5] = f2bf(a1.y); o[6] = f2bf(a1.z); o[7] = f2bf(a1.w);
        *(u16x8*)(xb + i) = o;
        return;
    }
    int tid = (blockIdx.x - XCB) * 256 + threadIdx.x;
    if (tid < 256 * 128) {
        int col = tid >> 7, k = tid & 127;
        float v = (col < 128) ? W1[k * 128 + col] : r1W[k * 128 + (col - 128)];
        Wb1t[col * 128 + k] = f2bf(v);
    } else if (tid < 256 * 128 + 80 * 128) {
        int t2 = tid - 256 * 128;
        int col = t2 >> 7, k = t2 & 127;
        float v = (col < NC) ? W2[k * NC + col] : r2W[k * NC + (col - NC)];
        Wb2t[col * 128 + k] = f2bf(v);
    } else {
        int t3 = tid - 256 * 128 - 80 * 128;
        if (t3 < 128) {
            float s = 0.f;
            for (int c = 0; c < NC; c++) s += W2[t3 * NC + c] * att_s2[c];
            wts[t3] = s;
            wtsb[t3] = f2bf(s);
        } else if (t3 < 256) {
            int k = t3 - 128;
            float s = 0.f;
            for (int c = 0; c < NC; c++) s += W2[k * NC + c] * att_d2[c];
            wtd[k] = s;
            wtdb[k] = f2bf(s);
        } else {
            int t4 = t3 - 256;
            if (t4 < NBUK) bukcnt[t4] = 0;
            else if (t4 == NBUK) rs[Nn] = EP;
        }
    }
}

// ---------------- fused: partA (CSR bucket scatter) || gemm1 (64 nodes/block, bf16 x, reg weights) ----------------

__global__ __launch_bounds__(256) void fused1_kernel(
        const unsigned short* __restrict__ xb, const unsigned short* __restrict__ Wb1t,
        const float* __restrict__ r1b,
        const float* __restrict__ att_s, const float* __restrict__ att_d,
        unsigned short* __restrict__ h1b, unsigned short* __restrict__ hbufb,
        float* __restrict__ as1, float* __restrict__ ad1,
        const int* __restrict__ ei, int* __restrict__ bukcnt,
        long long* __restrict__ pairs) {
    __shared__ int smem[NBUK * 2];
    if (blockIdx.x < NBA) {
        // ---- partA body (load-batched) ----
        int* cntA = smem;
        int* resA = smem + NBUK;
        int t = threadIdx.x;
        for (int i = t; i < NBUK; i += 256) cntA[i] = 0;
        __syncthreads();
        int e0 = blockIdx.x * CHA;
        int cnt = EP - e0; if (cnt > CHA) cnt = CHA;   // always a multiple of 4

        int4 dd[8];
        #pragma unroll
        for (int p = 0; p < 8; p++) {
            int k = t * 4 + p * 1024;
            int e = e0 + k;
            if (k < cnt) {
                if (e + 3 < Ee) {
                    dd[p] = *(const int4*)(ei + Ee + e);
                } else {
                    dd[p].x = (e     < Ee) ? ei[Ee + e]     : e     - Ee;
                    dd[p].y = (e + 1 < Ee) ? ei[Ee + e + 1] : e + 1 - Ee;
                    dd[p].z = (e + 2 < Ee) ? ei[Ee + e + 2] : e + 2 - Ee;
                    dd[p].w = (e + 3 < Ee) ? ei[Ee + e + 3] : e + 3 - Ee;
                }
            } else {
                dd[p] = (int4){-1, -1, -1, -1};
            }
        }
        #pragma unroll
        for (int p = 0; p < 8; p++) {
            if (dd[p].x >= 0) {
                atomicAdd(&cntA[dd[p].x >> 8], 1);
                atomicAdd(&cntA[dd[p].y >> 8], 1);
                atomicAdd(&cntA[dd[p].z >> 8], 1);
                atomicAdd(&cntA[dd[p].w >> 8], 1);
            }
        }
        __syncthreads();
        for (int b = t; b < NBUK; b += 256) {
            int c = cntA[b];
            resA[b] = c ? atomicAdd(&bukcnt[b], c) : 0;
            cntA[b] = 0;
        }
        __syncthreads();
        #pragma unroll
        for (int hf = 0; hf < 2; hf++) {
            int4 ss[4];
            #pragma unroll
            for (int p = 0; p < 4; p++) {
                int k = t * 4 + (hf * 4 + p) * 1024;
                int e = e0 + k;
                if (k < cnt) {
                    if (e + 3 < Ee) {
                        ss[p] = *(const int4*)(ei + e);
                    } else {
                        ss[p].x = (e     < Ee) ? ei[e]     : e     - Ee;
                        ss[p].y = (e + 1 < Ee) ? ei[e + 1] : e + 1 - Ee;
                        ss[p].z = (e + 2 < Ee) ? ei[e + 2] : e + 2 - Ee;
                        ss[p].w = (e + 3 < Ee) ? ei[e + 3] : e + 3 - Ee;
                    }
                }
            }
            #pragma unroll
            for (int p = 0; p < 4; p++) {
                int4 d = dd[hf * 4 + p];
                if (d.x >= 0) {
                    int b0 = d.x >> 8; int r0 = atomicAdd(&cntA[b0], 1);
                    pairs[(size_t)b0 * CAPB + resA[b0] + r0] = ((long long)d.x << 32) | (unsigned)ss[p].x;
                    int b1 = d.y >> 8; int r1 = atomicAdd(&cntA[b1], 1);
                    pairs[(size_t)b1 * CAPB + resA[b1] + r1] = ((long long)d.y << 32) | (unsigned)ss[p].y;
                    int b2 = d.z >> 8; int r2 = atomicAdd(&cntA[b2], 1);
                    pairs[(size_t)b2 * CAPB + resA[b2] + r2] = ((long long)d.z << 32) | (unsigned)ss[p].z;
                    int b3 = d.w >> 8; int r3 = atomicAdd(&cntA[b3], 1);
                    pairs[(size_t)b3 * CAPB + resA[b3] + r3] = ((long long)d.w << 32) | (unsigned)ss[p].w;
                }
            }
        }
    } else {
        // ---- gemm1 body: 64 nodes/block, bf16 x loads (no conversion), reg weights ----
        int lane = threadIdx.x & 63, wv = threadIdx.x >> 6;
        int m = lane & 15, q = lane >> 4;
        int nb = (blockIdx.x - NBA) * 64;

        bf16x8 bw[4][4];
        #pragma unroll
        for (int t = 0; t < 4; t++) {
            const unsigned short* bp = Wb1t + (size_t)((wv * 4 + t) * 16 + m) * 128 + q * 8;
            #pragma unroll
            for (int kk = 0; kk < 4; kk++)
                bw[t][kk] = *(const bf16x8*)(bp + kk * 32);
        }

        #pragma unroll
        for (int ng = 0; ng < 4; ng++) {
            int node = nb + ng * 16 + m;
            int nld = node < Nn ? node : Nn - 1;

            bf16x8 af[4];
            const unsigned short* xr = xb + (size_t)nld * 128 + q * 8;
            #pragma unroll
            for (int kk = 0; kk < 4; kk++)
                af[kk] = *(const bf16x8*)(xr + kk * 32);

            f32x4 acc[4];
            #pragma unroll
            for (int t = 0; t < 4; t++) acc[t] = (f32x4){0.f, 0.f, 0.f, 0.f};
            #pragma unroll
            for (int t = 0; t < 4; t++) {
                #pragma unroll
                for (int kk = 0; kk < 4; kk++)
                    acc[t] = __builtin_amdgcn_mfma_f32_16x16x32_bf16(bw[t][kk], af[kk], acc[t], 0, 0, 0);
            }

            if (node < Nn) {
                if (wv < 2) {
                    float psum[4], pdum[4];
                    #pragma unroll
                    for (int t = 0; t < 4; t++) {
                        int c0 = (wv * 4 + t) * 16 + q * 4;
                        ushort4 o;
                        o.x = f2bf(acc[t][0]); o.y = f2bf(acc[t][1]);
                        o.z = f2bf(acc[t][2]); o.w = f2bf(acc[t][3]);
                        *(ushort4*)(h1b + (size_t)node * 128 + c0) = o;
                        float4 s4 = *(const float4*)(att_s + c0);
                        float4 d4 = *(const float4*)(att_d + c0);
                        float ps = acc[t][0] * s4.x + acc[t][1] * s4.y + acc[t][2] * s4.z + acc[t][3] * s4.w;
                        float pd = acc[t][0] * d4.x + acc[t][1] * d4.y + acc[t][2] * d4.z + acc[t][3] * d4.w;
                        ps += __shfl_xor(ps, 16, 64); ps += __shfl_xor(ps, 32, 64);
                        pd += __shfl_xor(pd, 16, 64); pd += __shfl_xor(pd, 32, 64);
                        psum[t] = ps; pdum[t] = pd;
                    }
                    if (q == 0) {
                        float4 o; o.x = psum[0]; o.y = psum[1]; o.z = psum[2]; o.w = psum[3];
                        *(float4*)(as1 + (size_t)node * 8 + wv * 4) = o;
                    } else if (q == 1) {
                        float4 o; o.x = pdum[0]; o.y = pdum[1]; o.z = pdum[2]; o.w = pdum[3];
                        *(float4*)(ad1 + (size_t)node * 8 + wv * 4) = o;
                    }
                } else {
                    #pragma unroll
                    for (int t = 0; t < 4; t++) {
                        int cc0 = ((wv - 2) * 4 + t) * 16 + q * 4;
                        float4 b4 = *(const float4*)(r1b + cc0);
                        ushort4 o;
                        o.x = f2bf(acc[t][0] + b4.x); o.y = f2bf(acc[t][1] + b4.y);
                        o.z = f2bf(acc[t][2] + b4.z); o.w = f2bf(acc[t][3] + b4.w);
                        *(ushort4*)(hbufb + (size_t)node * 128 + cc0) = o;
                    }
                }
            }
        }
    }
}

// ---------------- phase B: 1024 threads, inline bucket prefix + per-node rs + CSR scatter ----------------

__global__ __launch_bounds__(1024) void partB_kernel(const long long* __restrict__ pairs,
                                                     const int* __restrict__ bukcnt,
                                                     int* __restrict__ rs,
                                                     int* __restrict__ csr) {
    __shared__ int lcnt[GSZ];
    __shared__ int lbase[GSZ];
    __shared__ int bsum[16];
    int b = blockIdx.x;
    int t = threadIdx.x;
    int node0 = b * GSZ;
    int nodes = Nn - node0; if (nodes > GSZ) nodes = GSZ;
    int acc = 0;
    for (int i = t; i < b; i += 1024) acc += bukcnt[i];
    #pragma unroll
    for (int st = 1; st < 64; st <<= 1) acc += __shfl_xor(acc, st, 64);
    if ((t & 63) == 0) bsum[t >> 6] = acc;
    if (t < GSZ) lcnt[t] = 0;
    __syncthreads();
    int bb = 0;
    #pragma unroll
    for (int i = 0; i < 16; i++) bb += bsum[i];
    int lo = b * CAPB;
    int hi = lo + bukcnt[b];
    for (int j = lo + t; j < hi; j += 1024) {
        int li = (int)(pairs[j] >> 32) - node0;
        atomicAdd(&lcnt[li], 1);
    }
    __syncthreads();
    int c = (t < GSZ) ? lcnt[t] : 0;
    if (t < GSZ) lbase[t] = c;
    __syncthreads();
    #pragma unroll
    for (int off = 1; off < 256; off <<= 1) {
        int u = (t >= off && t < GSZ) ? lbase[t - off] : 0;
        __syncthreads();
        if (t < GSZ) lbase[t] += u;
        __syncthreads();
    }
    if (t < GSZ) {
        int myBase = bb + lbase[t] - c;
        if (t < nodes) rs[node0 + t] = myBase;
        lbase[t] = myBase;
        lcnt[t] = 0;
    }
    __syncthreads();
    for (int j = lo + t; j < hi; j += 1024) {
        long long p = pairs[j];
        int li = (int)(p >> 32) - node0;
        int r = atomicAdd(&lcnt[li], 1);
        csr[lbase[li] + r] = (int)(p & 0xffffffffLL);
    }
}

// ---------------- layer 1 gather-aggregate: shuffle-free + csr/as pipeline (ps/pd moved to gemm2) ----------------

__global__ __launch_bounds__(256) void agg1_kernel(
        const int* __restrict__ rs, const int* __restrict__ csr,
        const float* __restrict__ as, const float* __restrict__ ad,
        const unsigned short* __restrict__ h1b, const float* __restrict__ bias,
        const unsigned short* __restrict__ hbufb, unsigned short* __restrict__ hb) {
    int lane = threadIdx.x & 63, wv = threadIdx.x >> 6;
    int n = blockIdx.x * 4 + wv;
    if (n >= Nn) return;
    int row = rs[n], end = rs[n + 1];
    int slot = lane >> 3;
    int h = lane & 7;
    float adh = ad[n * 8 + h];
    const unsigned short* hcol = h1b + h * 16;

    float a[16];
    #pragma unroll
    for (int i = 0; i < 16; i++) a[i] = 0.f;
    float den = 0.f;

    // software-pipelined: csr AND as-gather for the current chunk load one iteration ahead
    bool v = slot < end - row;
    int sl = v ? csr[row + slot] : 0;
    float asv = as[sl * 8 + h];
    for (int j = row; j < end; j += 8) {
        bool cv = v;
        int cur = sl;
        float casv = asv;
        int jn = j + 8;
        if (jn < end) {
            v = slot < end - jn;
            sl = v ? csr[jn + slot] : 0;
            asv = as[sl * 8 + h];
        }
        float lg = casv + adh;
        lg = fmaxf(lg, SLOPE * lg);
        float e = cv ? __expf(lg) : 0.f;
        den += e;
        const unsigned short* p = hcol + (size_t)cur * 128;
        u32x4 u0 = *(const u32x4*)(p);
        u32x4 u1 = *(const u32x4*)(p + 8);
        #pragma unroll
        for (int k = 0; k < 4; k++) {
            unsigned u = u0[k];
            a[2 * k]     += e * __uint_as_float(u << 16);
            a[2 * k + 1] += e * __uint_as_float(u & 0xffff0000u);
            unsigned w = u1[k];
            a[8 + 2 * k]     += e * __uint_as_float(w << 16);
            a[8 + 2 * k + 1] += e * __uint_as_float(w & 0xffff0000u);
        }
    }

    den += __shfl_xor(den, 8, 64);
    den += __shfl_xor(den, 16, 64);
    den += __shfl_xor(den, 32, 64);
    float inv = 1.f / den;

    int l3 = (lane >> 3) & 1, l4 = (lane >> 4) & 1, l5 = (lane >> 5) & 1;
    float b8[8];
    #pragma unroll
    for (int i = 0; i < 8; i++) {
        float mine = l3 ? a[i + 8] : a[i];
        float send = l3 ? a[i] : a[i + 8];
        b8[i] = mine + __shfl_xor(send, 8, 64);
    }
    float b4[4];
    #pragma unroll
    for (int i = 0; i < 4; i++) {
        float mine = l4 ? b8[i + 4] : b8[i];
        float send = l4 ? b8[i] : b8[i + 4];
        b4[i] = mine + __shfl_xor(send, 16, 64);
    }
    float c2[2];
    #pragma unroll
    for (int i = 0; i < 2; i++) {
        float mine = l5 ? b4[i + 2] : b4[i];
        float send = l5 ? b4[i] : b4[i + 2];
        c2[i] = mine + __shfl_xor(send, 32, 64);
    }
    int c0 = h * 16 + l3 * 8 + l4 * 4 + l5 * 2;

    float g0 = c2[0] * inv + bias[c0];
    float g1 = c2[1] * inv + bias[c0 + 1];
    unsigned rr = *(const unsigned*)(hbufb + (size_t)n * 128 + c0);
    g0 = (g0 > 0.f ? g0 : __expf(g0) - 1.f) + __uint_as_float(rr << 16);
    g1 = (g1 > 0.f ? g1 : __expf(g1) - 1.f) + __uint_as_float(rr & 0xffff0000u);
    unsigned o = ((unsigned)f2bf(g0)) | (((unsigned)f2bf(g1)) << 16);
    *(unsigned*)(hb + (size_t)n * 128 + c0) = o;
}

// ---------------- layer 2 GEMM: 64 nodes/block, reg weights, + as2/ad2 via extra MFMA ----------------

__global__ __launch_bounds__(320) void gemm2_kernel(
        const unsigned short* __restrict__ hb, const unsigned short* __restrict__ Wb2t,
        const float* __restrict__ r2b,
        const unsigned short* __restrict__ wtsb, const unsigned short* __restrict__ wtdb,
        unsigned short* __restrict__ h2b, float* __restrict__ outp,
        float* __restrict__ as2, float* __restrict__ ad2) {
    int lane = threadIdx.x & 63, wv = threadIdx.x >> 6;   // wv 0..4
    int m = lane & 15, q = lane >> 4;
    int nb = blockIdx.x * 64;

    bf16x8 bw[4];
    const unsigned short* bp = Wb2t + (size_t)(wv * 16 + m) * 128 + q * 8;
    #pragma unroll
    for (int kk = 0; kk < 4; kk++) bw[kk] = *(const bf16x8*)(bp + kk * 32);

    // wv0: B-fragment carrying wts (col 0) / wtd (col 1) for the score-dot MFMA
    bf16x8 wf[4];
    if (wv == 0) {
        #pragma unroll
        for (int kk = 0; kk < 4; kk++) {
            if (m == 0)      wf[kk] = *(const bf16x8*)(wtsb + kk * 32 + q * 8);
            else if (m == 1) wf[kk] = *(const bf16x8*)(wtdb + kk * 32 + q * 8);
            else             wf[kk] = (bf16x8){0, 0, 0, 0, 0, 0, 0, 0};
        }
    }

    #pragma unroll
    for (int ng = 0; ng < 4; ng++) {
        int node = nb + ng * 16 + m;
        int nld = node < Nn ? node : Nn - 1;
        const unsigned short* hr = hb + (size_t)nld * 128 + q * 8;
        bf16x8 av[4];
        #pragma unroll
        for (int kk = 0; kk < 4; kk++) av[kk] = *(const bf16x8*)(hr + kk * 32);

        f32x4 acc = (f32x4){0.f, 0.f, 0.f, 0.f};
        #pragma unroll
        for (int kk = 0; kk < 4; kk++)
            acc = __builtin_amdgcn_mfma_f32_16x16x32_bf16(bw[kk], av[kk], acc, 0, 0, 0);

        if (node < Nn) {
            int f0 = wv * 16 + q * 4;
            if (f0 < NC) {
                ushort4 o;
                o.x = f2bf(acc[0]); o.y = f2bf(acc[1]);
                o.z = f2bf(acc[2]); o.w = f2bf(acc[3]);
                *(ushort4*)(h2b + (size_t)node * 64 + f0) = o;
            } else {
                int cc = f0 - NC;
                float4 b4 = *(const float4*)(r2b + cc);
                float4 o;
                o.x = acc[0] + b4.x; o.y = acc[1] + b4.y;
                o.z = acc[2] + b4.z; o.w = acc[3] + b4.w;
                *(float4*)(outp + (size_t)node * NC + cc) = o;
            }
        }

        if (wv == 0) {
            // D[node][0/1] = hb[node] . wts/wtd : A=av (node rows), B=wf
            f32x4 acc2 = (f32x4){0.f, 0.f, 0.f, 0.f};
            #pragma unroll
            for (int kk = 0; kk < 4; kk++)
                acc2 = __builtin_amdgcn_mfma_f32_16x16x32_bf16(av[kk], wf[kk], acc2, 0, 0, 0);
            if (m < 2) {
                float* dst = (m == 0) ? as2 : ad2;
                #pragma unroll
                for (int r = 0; r < 4; r++) {
                    int nn = nb + ng * 16 + q * 4 + r;
                    if (nn < Nn) dst[nn] = acc2[r];
                }
            }
        }
    }
}

// ---------------- layer 2 gather-aggregate: shuffle-free + csr/as pipeline + log_softmax ----------------

__global__ __launch_bounds__(256) void agg2_kernel(
        const int* __restrict__ rs, const int* __restrict__ csr,
        const float* __restrict__ as, const float* __restrict__ ad,
        const unsigned short* __restrict__ h2b, const float* __restrict__ b2,
        float* __restrict__ outp) {
    int lane = threadIdx.x & 63, wv = threadIdx.x >> 6;
    int n = blockIdx.x * 4 + wv;
    if (n >= Nn) return;
    int row = rs[n], end = rs[n + 1];
    float adn = ad[n];
    int slot = lane >> 3, h = lane & 7;
    const unsigned short* hcol = h2b + h * 8;

    float a[8];
    #pragma unroll
    for (int i = 0; i < 8; i++) a[i] = 0.f;
    float den = 0.f;

    bool v = slot < end - row;
    int sl = v ? csr[row + slot] : 0;
    float asv = as[sl];
    for (int j = row; j < end; j += 8) {
        bool cv = v;
        int cur = sl;
        float casv = asv;
        int jn = j + 8;
        if (jn < end) {
            v = slot < end - jn;
            sl = v ? csr[jn + slot] : 0;
            asv = as[sl];
        }
        float lg = casv + adn;
        lg = fmaxf(lg, SLOPE * lg);
        float e = cv ? __expf(lg) : 0.f;
        den += e;
        u32x4 u0 = *(const u32x4*)(hcol + (size_t)cur * 64);
        #pragma unroll
        for (int k = 0; k < 4; k++) {
            unsigned u = u0[k];
            a[2 * k]     += e * __uint_as_float(u << 16);
            a[2 * k + 1] += e * __uint_as_float(u & 0xffff0000u);
        }
    }

    den += __shfl_xor(den, 8, 64);
    den += __shfl_xor(den, 16, 64);
    den += __shfl_xor(den, 32, 64);
    float inv = 1.f / den;

    int l3 = (lane >> 3) & 1, l4 = (lane >> 4) & 1, l5 = (lane >> 5) & 1;
    float c4[4];
    #pragma unroll
    for (int i = 0; i < 4; i++) {
        float mine = l3 ? a[i + 4] : a[i];
        float send = l3 ? a[i] : a[i + 4];
        c4[i] = mine + __shfl_xor(send, 8, 64);
    }
    float c2[2];
    #pragma unroll
    for (int i = 0; i < 2; i++) {
        float mine = l4 ? c4[i + 2] : c4[i];
        float send = l4 ? c4[i] : c4[i + 2];
        c2[i] = mine + __shfl_xor(send, 16, 64);
    }
    float mine = l5 ? c2[1] : c2[0];
    float send = l5 ? c2[0] : c2[1];
    float av = mine + __shfl_xor(send, 32, 64);
    int c = h * 8 + l3 * 4 + l4 * 2 + l5;
    bool act = c < NC;

    float v0 = -3.4e38f;
    if (act) v0 = av * inv + b2[c] + outp[(size_t)n * NC + c];
    float mm = v0;
    #pragma unroll
    for (int st = 32; st >= 1; st >>= 1) mm = fmaxf(mm, __shfl_xor(mm, st, 64));
    float ex = act ? __expf(v0 - mm) : 0.f;
    float ss = ex;
    #pragma unroll
    for (int st = 32; st >= 1; st >>= 1) ss += __shfl_xor(ss, st, 64);
    if (act) {
        float lg = mm + logf(ss);
        outp[(size_t)n * NC + c] = v0 - lg;
    }
}

// ---------------- host ----------------

extern "C" void kernel_launch(void* const* d_in, const int* in_sizes, int n_in,
                              void* d_out, int out_size, void* d_ws, size_t ws_size,
                              hipStream_t stream) {
    const float* x      = (const float*)d_in[0];
    const int*   ei     = (const int*)d_in[1];
    const float* W1     = (const float*)d_in[2];
    const float* att_s1 = (const float*)d_in[3];
    const float* att_d1 = (const float*)d_in[4];
    const float* bias1  = (const float*)d_in[5];
    const float* W2     = (const float*)d_in[6];
    const float* att_s2 = (const float*)d_in[7];
    const float* att_d2 = (const float*)d_in[8];
    const float* bias2  = (const float*)d_in[9];
    const float* r1W    = (const float*)d_in[10];
    const float* r1b    = (const float*)d_in[11];
    const float* r2W    = (const float*)d_in[12];
    const float* r2b    = (const float*)d_in[13];
    float* out = (float*)d_out;

    float* ws   = (float*)d_ws;
    float* as1  = ws;                            // N*8
    float* ad1  = as1 + (size_t)Nn * 8;          // N*8
    float* as2  = ad1 + (size_t)Nn * 8;          // N
    float* ad2  = as2 + Nn;                      // N
    float* wts  = ad2 + Nn;                      // 128
    float* wtd  = wts + 128;                     // 128
    unsigned short* wtsb = (unsigned short*)(wtd + 128);   // 128 bf16
    unsigned short* wtdb = wtsb + 128;                     // 128 bf16
    unsigned short* hbufb = wtdb + 128;                    // N*128 bf16 (res1)
    unsigned short* h1b = hbufb + (size_t)Nn * 128;        // N*128 bf16
    unsigned short* hb  = h1b + (size_t)Nn * 128;          // N*128 bf16 (post-agg1 h)
    unsigned short* Wb1t = hb + (size_t)Nn * 128;          // 256*128 bf16
    unsigned short* Wb2t = Wb1t + 256 * 128;               // 80*128 bf16
    unsigned short* xb   = Wb2t + 80 * 128;                // N*128 bf16 (pre-cast x)
    uintptr_t pal = ((uintptr_t)(xb + (size_t)Nn * 128) + 15) & ~(uintptr_t)15;
    long long* pairs = (long long*)pal;          // NBUK*CAPB pairs (dead after partB)
    unsigned short* h2b = (unsigned short*)pal;  // N*64 bf16, ALIASES pairs (used after partB)
    int* rs      = (int*)(pairs + (size_t)NBUK * CAPB);  // N+1
    int* bukcnt  = rs + Nn + 1;                  // NBUK
    int* csr     = bukcnt + NBUK;                // EP

    // ---- x->bf16 + weight prep + bukcnt zero + rs[Nn] ----
    castW_kernel<<<XCB + (256 * 128 + 80 * 128 + 256 + NBUK + 1 + 255) / 256, 256, 0, stream>>>(
        x, xb, W1, r1W, W2, r2W, att_s2, att_d2, Wb1t, Wb2t, wts, wtd, wtsb, wtdb, bukcnt, rs);

    // ---- partA || gemm1 (independent, overlapped) ----
    fused1_kernel<<<NBA + G1B, 256, 0, stream>>>(xb, Wb1t, r1b, att_s1, att_d1,
                                                 h1b, hbufb, as1, ad1,
                                                 ei, bukcnt, pairs);

    // ---- CSR finalize ----
    partB_kernel<<<NBUK, 1024, 0, stream>>>(pairs, bukcnt, rs, csr);

    // ---- layer 1 aggregate ----
    agg1_kernel<<<(Nn + 3) / 4, 256, 0, stream>>>(rs, csr, as1, ad1, h1b, bias1,
                                                  hbufb, hb);

    // ---- layer 2 (as2/ad2 computed in-GEMM via extra MFMA) ----
    gemm2_kernel<<<(Nn + 63) / 64, 320, 0, stream>>>(hb, Wb2t, r2b, wtsb, wtdb,
                                                     h2b, out, as2, ad2);
    agg2_kernel<<<(Nn + 3) / 4, 256, 0, stream>>>(rs, csr, as2, ad2, h2b, bias2, out);
}

// Round 13
// 350.768 us; speedup vs baseline: 1.0401x; 1.0064x over previous
//
#include <hip/hip_runtime.h>
#include <math.h>

#define Nn 100000
#define Ee 1600000
#define EP 1700000   /* Ee + Nn self loops */
#define NC 40
#define SLOPE 0.2f
#define GSZ 256      /* nodes per bucket */
#define NBUK 391     /* ceil(Nn/GSZ) */
#define CAPB 8192    /* padded capacity per bucket */
#define CHA 8192     /* edges per partition block */
#define NBA ((EP + CHA - 1) / CHA)
#define G1B ((Nn + 63) / 64)   /* 64 nodes per gemm block */
#define XCB 6250     /* castW blocks converting x: 100000*128/8/256 */

typedef short bf16x8 __attribute__((ext_vector_type(8)));
typedef unsigned short u16x8 __attribute__((ext_vector_type(8)));
typedef float f32x4 __attribute__((ext_vector_type(4)));
typedef unsigned int u32x4 __attribute__((ext_vector_type(4)));

// ---------- bf16 helpers ----------

__device__ __forceinline__ unsigned short f2bf(float f) {
    unsigned u = __float_as_uint(f);
    unsigned r = u + 0x7FFFu + ((u >> 16) & 1u);
    return (unsigned short)(r >> 16);
}
__device__ __forceinline__ float bf2f(unsigned short u) {
    return __uint_as_float(((unsigned)u) << 16);
}

// ---------------- x->bf16 + weight cast/transpose + w~ vectors (f32 + bf16) + bukcnt zero + rs[Nn] ----------------

__global__ void castW_kernel(const float* __restrict__ x, unsigned short* __restrict__ xb,
                             const float* __restrict__ W1, const float* __restrict__ r1W,
                             const float* __restrict__ W2, const float* __restrict__ r2W,
                             const float* __restrict__ att_s2, const float* __restrict__ att_d2,
                             unsigned short* __restrict__ Wb1t, unsigned short* __restrict__ Wb2t,
                             float* __restrict__ wts, float* __restrict__ wtd,
                             unsigned short* __restrict__ wtsb, unsigned short* __restrict__ wtdb,
                             int* __restrict__ bukcnt, int* __restrict__ rs) {
    if (blockIdx.x < XCB) {
        size_t i = ((size_t)blockIdx.x * 256 + threadIdx.x) * 8;
        float4 a0 = *(const float4*)(x + i);
        float4 a1 = *(const float4*)(x + i + 4);
        u16x8 o;
        o[0] = f2bf(a0.x); o[1] = f2bf(a0.y); o[2] = f2bf(a0.z); o[3] = f2bf(a0.w);
        o[4] = f2bf(a1.x); o[5] = f2bf(a1.y); o[6] = f2bf(a1.z); o[7] = f2bf(a1.w);
        *(u16x8*)(xb + i) = o;
        return;
    }
    int tid = (blockIdx.x - XCB) * 256 + threadIdx.x;
    if (tid < 256 * 128) {
        int col = tid >> 7, k = tid & 127;
        float v = (col < 128) ? W1[k * 128 + col] : r1W[k * 128 + (col - 128)];
        Wb1t[col * 128 + k] = f2bf(v);
    } else if (tid < 256 * 128 + 80 * 128) {
        int t2 = tid - 256 * 128;
        int col = t2 >> 7, k = t2 & 127;
        float v = (col < NC) ? W2[k * NC + col] : r2W[k * NC + (col - NC)];
        Wb2t[col * 128 + k] = f2bf(v);
    } else {
        int t3 = tid - 256 * 128 - 80 * 128;
        if (t3 < 128) {
            float s = 0.f;
            for (int c = 0; c < NC; c++) s += W2[t3 * NC + c] * att_s2[c];
            wts[t3] = s;
            wtsb[t3] = f2bf(s);
        } else if (t3 < 256) {
            int k = t3 - 128;
            float s = 0.f;
            for (int c = 0; c < NC; c++) s += W2[k * NC + c] * att_d2[c];
            wtd[k] = s;
            wtdb[k] = f2bf(s);
        } else {
            int t4 = t3 - 256;
            if (t4 < NBUK) bukcnt[t4] = 0;
            else if (t4 == NBUK) rs[Nn] = EP;
        }
    }
}

// ---------------- fused: partA (CSR bucket scatter) || gemm1 (64 nodes/block, bf16 x, reg weights) ----------------

__global__ __launch_bounds__(256) void fused1_kernel(
        const unsigned short* __restrict__ xb, const unsigned short* __restrict__ Wb1t,
        const float* __restrict__ r1b,
        const float* __restrict__ att_s, const float* __restrict__ att_d,
        unsigned short* __restrict__ h1b, unsigned short* __restrict__ hbufb,
        float* __restrict__ as1, float* __restrict__ ad1,
        const int* __restrict__ ei, int* __restrict__ bukcnt,
        long long* __restrict__ pairs) {
    __shared__ int smem[NBUK * 2];
    if (blockIdx.x < NBA) {
        // ---- partA body (load-batched) ----
        int* cntA = smem;
        int* resA = smem + NBUK;
        int t = threadIdx.x;
        for (int i = t; i < NBUK; i += 256) cntA[i] = 0;
        __syncthreads();
        int e0 = blockIdx.x * CHA;
        int cnt = EP - e0; if (cnt > CHA) cnt = CHA;   // always a multiple of 4

        int4 dd[8];
        #pragma unroll
        for (int p = 0; p < 8; p++) {
            int k = t * 4 + p * 1024;
            int e = e0 + k;
            if (k < cnt) {
                if (e + 3 < Ee) {
                    dd[p] = *(const int4*)(ei + Ee + e);
                } else {
                    dd[p].x = (e     < Ee) ? ei[Ee + e]     : e     - Ee;
                    dd[p].y = (e + 1 < Ee) ? ei[Ee + e + 1] : e + 1 - Ee;
                    dd[p].z = (e + 2 < Ee) ? ei[Ee + e + 2] : e + 2 - Ee;
                    dd[p].w = (e + 3 < Ee) ? ei[Ee + e + 3] : e + 3 - Ee;
                }
            } else {
                dd[p] = (int4){-1, -1, -1, -1};
            }
        }
        #pragma unroll
        for (int p = 0; p < 8; p++) {
            if (dd[p].x >= 0) {
                atomicAdd(&cntA[dd[p].x >> 8], 1);
                atomicAdd(&cntA[dd[p].y >> 8], 1);
                atomicAdd(&cntA[dd[p].z >> 8], 1);
                atomicAdd(&cntA[dd[p].w >> 8], 1);
            }
        }
        __syncthreads();
        for (int b = t; b < NBUK; b += 256) {
            int c = cntA[b];
            resA[b] = c ? atomicAdd(&bukcnt[b], c) : 0;
            cntA[b] = 0;
        }
        __syncthreads();
        #pragma unroll
        for (int hf = 0; hf < 2; hf++) {
            int4 ss[4];
            #pragma unroll
            for (int p = 0; p < 4; p++) {
                int k = t * 4 + (hf * 4 + p) * 1024;
                int e = e0 + k;
                if (k < cnt) {
                    if (e + 3 < Ee) {
                        ss[p] = *(const int4*)(ei + e);
                    } else {
                        ss[p].x = (e     < Ee) ? ei[e]     : e     - Ee;
                        ss[p].y = (e + 1 < Ee) ? ei[e + 1] : e + 1 - Ee;
                        ss[p].z = (e + 2 < Ee) ? ei[e + 2] : e + 2 - Ee;
                        ss[p].w = (e + 3 < Ee) ? ei[e + 3] : e + 3 - Ee;
                    }
                }
            }
            #pragma unroll
            for (int p = 0; p < 4; p++) {
                int4 d = dd[hf * 4 + p];
                if (d.x >= 0) {
                    int b0 = d.x >> 8; int r0 = atomicAdd(&cntA[b0], 1);
                    pairs[(size_t)b0 * CAPB + resA[b0] + r0] = ((long long)d.x << 32) | (unsigned)ss[p].x;
                    int b1 = d.y >> 8; int r1 = atomicAdd(&cntA[b1], 1);
                    pairs[(size_t)b1 * CAPB + resA[b1] + r1] = ((long long)d.y << 32) | (unsigned)ss[p].y;
                    int b2 = d.z >> 8; int r2 = atomicAdd(&cntA[b2], 1);
                    pairs[(size_t)b2 * CAPB + resA[b2] + r2] = ((long long)d.z << 32) | (unsigned)ss[p].z;
                    int b3 = d.w >> 8; int r3 = atomicAdd(&cntA[b3], 1);
                    pairs[(size_t)b3 * CAPB + resA[b3] + r3] = ((long long)d.w << 32) | (unsigned)ss[p].w;
                }
            }
        }
    } else {
        // ---- gemm1 body: 64 nodes/block, bf16 x loads (no conversion), reg weights ----
        int lane = threadIdx.x & 63, wv = threadIdx.x >> 6;
        int m = lane & 15, q = lane >> 4;
        int nb = (blockIdx.x - NBA) * 64;

        bf16x8 bw[4][4];
        #pragma unroll
        for (int t = 0; t < 4; t++) {
            const unsigned short* bp = Wb1t + (size_t)((wv * 4 + t) * 16 + m) * 128 + q * 8;
            #pragma unroll
            for (int kk = 0; kk < 4; kk++)
                bw[t][kk] = *(const bf16x8*)(bp + kk * 32);
        }

        #pragma unroll
        for (int ng = 0; ng < 4; ng++) {
            int node = nb + ng * 16 + m;
            int nld = node < Nn ? node : Nn - 1;

            bf16x8 af[4];
            const unsigned short* xr = xb + (size_t)nld * 128 + q * 8;
            #pragma unroll
            for (int kk = 0; kk < 4; kk++)
                af[kk] = *(const bf16x8*)(xr + kk * 32);

            f32x4 acc[4];
            #pragma unroll
            for (int t = 0; t < 4; t++) acc[t] = (f32x4){0.f, 0.f, 0.f, 0.f};
            #pragma unroll
            for (int t = 0; t < 4; t++) {
                #pragma unroll
                for (int kk = 0; kk < 4; kk++)
                    acc[t] = __builtin_amdgcn_mfma_f32_16x16x32_bf16(bw[t][kk], af[kk], acc[t], 0, 0, 0);
            }

            if (node < Nn) {
                if (wv < 2) {
                    float psum[4], pdum[4];
                    #pragma unroll
                    for (int t = 0; t < 4; t++) {
                        int c0 = (wv * 4 + t) * 16 + q * 4;
                        ushort4 o;
                        o.x = f2bf(acc[t][0]); o.y = f2bf(acc[t][1]);
                        o.z = f2bf(acc[t][2]); o.w = f2bf(acc[t][3]);
                        *(ushort4*)(h1b + (size_t)node * 128 + c0) = o;
                        float4 s4 = *(const float4*)(att_s + c0);
                        float4 d4 = *(const float4*)(att_d + c0);
                        float ps = acc[t][0] * s4.x + acc[t][1] * s4.y + acc[t][2] * s4.z + acc[t][3] * s4.w;
                        float pd = acc[t][0] * d4.x + acc[t][1] * d4.y + acc[t][2] * d4.z + acc[t][3] * d4.w;
                        ps += __shfl_xor(ps, 16, 64); ps += __shfl_xor(ps, 32, 64);
                        pd += __shfl_xor(pd, 16, 64); pd += __shfl_xor(pd, 32, 64);
                        psum[t] = ps; pdum[t] = pd;
                    }
                    if (q == 0) {
                        float4 o; o.x = psum[0]; o.y = psum[1]; o.z = psum[2]; o.w = psum[3];
                        *(float4*)(as1 + (size_t)node * 8 + wv * 4) = o;
                    } else if (q == 1) {
                        float4 o; o.x = pdum[0]; o.y = pdum[1]; o.z = pdum[2]; o.w = pdum[3];
                        *(float4*)(ad1 + (size_t)node * 8 + wv * 4) = o;
                    }
                } else {
                    #pragma unroll
                    for (int t = 0; t < 4; t++) {
                        int cc0 = ((wv - 2) * 4 + t) * 16 + q * 4;
                        float4 b4 = *(const float4*)(r1b + cc0);
                        ushort4 o;
                        o.x = f2bf(acc[t][0] + b4.x); o.y = f2bf(acc[t][1] + b4.y);
                        o.z = f2bf(acc[t][2] + b4.z); o.w = f2bf(acc[t][3] + b4.w);
                        *(ushort4*)(hbufb + (size_t)node * 128 + cc0) = o;
                    }
                }
            }
        }
    }
}

// ---------------- phase B: 1024 threads, inline bucket prefix + per-node rs + CSR scatter ----------------

__global__ __launch_bounds__(1024) void partB_kernel(const long long* __restrict__ pairs,
                                                     const int* __restrict__ bukcnt,
                                                     int* __restrict__ rs,
                                                     int* __restrict__ csr) {
    __shared__ int lcnt[GSZ];
    __shared__ int lbase[GSZ];
    __shared__ int bsum[16];
    int b = blockIdx.x;
    int t = threadIdx.x;
    int node0 = b * GSZ;
    int nodes = Nn - node0; if (nodes > GSZ) nodes = GSZ;
    int acc = 0;
    for (int i = t; i < b; i += 1024) acc += bukcnt[i];
    #pragma unroll
    for (int st = 1; st < 64; st <<= 1) acc += __shfl_xor(acc, st, 64);
    if ((t & 63) == 0) bsum[t >> 6] = acc;
    if (t < GSZ) lcnt[t] = 0;
    __syncthreads();
    int bb = 0;
    #pragma unroll
    for (int i = 0; i < 16; i++) bb += bsum[i];
    int lo = b * CAPB;
    int hi = lo + bukcnt[b];
    for (int j = lo + t; j < hi; j += 1024) {
        int li = (int)(pairs[j] >> 32) - node0;
        atomicAdd(&lcnt[li], 1);
    }
    __syncthreads();
    int c = (t < GSZ) ? lcnt[t] : 0;
    if (t < GSZ) lbase[t] = c;
    __syncthreads();
    #pragma unroll
    for (int off = 1; off < 256; off <<= 1) {
        int u = (t >= off && t < GSZ) ? lbase[t - off] : 0;
        __syncthreads();
        if (t < GSZ) lbase[t] += u;
        __syncthreads();
    }
    if (t < GSZ) {
        int myBase = bb + lbase[t] - c;
        if (t < nodes) rs[node0 + t] = myBase;
        lbase[t] = myBase;
        lcnt[t] = 0;
    }
    __syncthreads();
    for (int j = lo + t; j < hi; j += 1024) {
        long long p = pairs[j];
        int li = (int)(p >> 32) - node0;
        int r = atomicAdd(&lcnt[li], 1);
        csr[lbase[li] + r] = (int)(p & 0xffffffffLL);
    }
}

// ---------------- layer 1 gather-aggregate: full pipeline (csr/as AND payload one chunk ahead) ----------------

__global__ __launch_bounds__(256) void agg1_kernel(
        const int* __restrict__ rs, const int* __restrict__ csr,
        const float* __restrict__ as, const float* __restrict__ ad,
        const unsigned short* __restrict__ h1b, const float* __restrict__ bias,
        const unsigned short* __restrict__ hbufb, unsigned short* __restrict__ hb) {
    int lane = threadIdx.x & 63, wv = threadIdx.x >> 6;
    int n = blockIdx.x * 4 + wv;
    if (n >= Nn) return;
    int row = rs[n], end = rs[n + 1];
    int slot = lane >> 3;
    int h = lane & 7;
    float adh = ad[n * 8 + h];
    const unsigned short* hcol = h1b + h * 16;

    float a[16];
    #pragma unroll
    for (int i = 0; i < 16; i++) a[i] = 0.f;
    float den = 0.f;

    // prologue: issue csr/as AND payload loads for chunk 0
    bool v = slot < end - row;
    int sl = v ? csr[row + slot] : 0;
    float asv = as[sl * 8 + h];
    const unsigned short* pp = hcol + (size_t)sl * 128;
    u32x4 cu0 = *(const u32x4*)(pp);
    u32x4 cu1 = *(const u32x4*)(pp + 8);

    for (int j = row; j < end; j += 8) {
        bool cv = v;
        float casv = asv;
        u32x4 u0 = cu0, u1 = cu1;
        int jn = j + 8;
        if (jn < end) {
            v = slot < end - jn;
            sl = v ? csr[jn + slot] : 0;
            asv = as[sl * 8 + h];
            const unsigned short* pn = hcol + (size_t)sl * 128;
            cu0 = *(const u32x4*)(pn);
            cu1 = *(const u32x4*)(pn + 8);
        }
        float lg = casv + adh;
        lg = fmaxf(lg, SLOPE * lg);
        float e = cv ? __expf(lg) : 0.f;
        den += e;
        #pragma unroll
        for (int k = 0; k < 4; k++) {
            unsigned u = u0[k];
            a[2 * k]     += e * __uint_as_float(u << 16);
            a[2 * k + 1] += e * __uint_as_float(u & 0xffff0000u);
            unsigned w = u1[k];
            a[8 + 2 * k]     += e * __uint_as_float(w << 16);
            a[8 + 2 * k + 1] += e * __uint_as_float(w & 0xffff0000u);
        }
    }

    den += __shfl_xor(den, 8, 64);
    den += __shfl_xor(den, 16, 64);
    den += __shfl_xor(den, 32, 64);
    float inv = 1.f / den;

    int l3 = (lane >> 3) & 1, l4 = (lane >> 4) & 1, l5 = (lane >> 5) & 1;
    float b8[8];
    #pragma unroll
    for (int i = 0; i < 8; i++) {
        float mine = l3 ? a[i + 8] : a[i];
        float send = l3 ? a[i] : a[i + 8];
        b8[i] = mine + __shfl_xor(send, 8, 64);
    }
    float b4[4];
    #pragma unroll
    for (int i = 0; i < 4; i++) {
        float mine = l4 ? b8[i + 4] : b8[i];
        float send = l4 ? b8[i] : b8[i + 4];
        b4[i] = mine + __shfl_xor(send, 16, 64);
    }
    float c2[2];
    #pragma unroll
    for (int i = 0; i < 2; i++) {
        float mine = l5 ? b4[i + 2] : b4[i];
        float send = l5 ? b4[i] : b4[i + 2];
        c2[i] = mine + __shfl_xor(send, 32, 64);
    }
    int c0 = h * 16 + l3 * 8 + l4 * 4 + l5 * 2;

    float g0 = c2[0] * inv + bias[c0];
    float g1 = c2[1] * inv + bias[c0 + 1];
    unsigned rr = *(const unsigned*)(hbufb + (size_t)n * 128 + c0);
    g0 = (g0 > 0.f ? g0 : __expf(g0) - 1.f) + __uint_as_float(rr << 16);
    g1 = (g1 > 0.f ? g1 : __expf(g1) - 1.f) + __uint_as_float(rr & 0xffff0000u);
    unsigned o = ((unsigned)f2bf(g0)) | (((unsigned)f2bf(g1)) << 16);
    *(unsigned*)(hb + (size_t)n * 128 + c0) = o;
}

// ---------------- layer 2 GEMM: 64 nodes/block, reg weights, + as2/ad2 via extra MFMA ----------------

__global__ __launch_bounds__(320) void gemm2_kernel(
        const unsigned short* __restrict__ hb, const unsigned short* __restrict__ Wb2t,
        const float* __restrict__ r2b,
        const unsigned short* __restrict__ wtsb, const unsigned short* __restrict__ wtdb,
        unsigned short* __restrict__ h2b, float* __restrict__ outp,
        float* __restrict__ as2, float* __restrict__ ad2) {
    int lane = threadIdx.x & 63, wv = threadIdx.x >> 6;   // wv 0..4
    int m = lane & 15, q = lane >> 4;
    int nb = blockIdx.x * 64;

    bf16x8 bw[4];
    const unsigned short* bp = Wb2t + (size_t)(wv * 16 + m) * 128 + q * 8;
    #pragma unroll
    for (int kk = 0; kk < 4; kk++) bw[kk] = *(const bf16x8*)(bp + kk * 32);

    // wv0: B-fragment carrying wts (col 0) / wtd (col 1) for the score-dot MFMA
    bf16x8 wf[4];
    if (wv == 0) {
        #pragma unroll
        for (int kk = 0; kk < 4; kk++) {
            if (m == 0)      wf[kk] = *(const bf16x8*)(wtsb + kk * 32 + q * 8);
            else if (m == 1) wf[kk] = *(const bf16x8*)(wtdb + kk * 32 + q * 8);
            else             wf[kk] = (bf16x8){0, 0, 0, 0, 0, 0, 0, 0};
        }
    }

    #pragma unroll
    for (int ng = 0; ng < 4; ng++) {
        int node = nb + ng * 16 + m;
        int nld = node < Nn ? node : Nn - 1;
        const unsigned short* hr = hb + (size_t)nld * 128 + q * 8;
        bf16x8 av[4];
        #pragma unroll
        for (int kk = 0; kk < 4; kk++) av[kk] = *(const bf16x8*)(hr + kk * 32);

        f32x4 acc = (f32x4){0.f, 0.f, 0.f, 0.f};
        #pragma unroll
        for (int kk = 0; kk < 4; kk++)
            acc = __builtin_amdgcn_mfma_f32_16x16x32_bf16(bw[kk], av[kk], acc, 0, 0, 0);

        if (node < Nn) {
            int f0 = wv * 16 + q * 4;
            if (f0 < NC) {
                ushort4 o;
                o.x = f2bf(acc[0]); o.y = f2bf(acc[1]);
                o.z = f2bf(acc[2]); o.w = f2bf(acc[3]);
                *(ushort4*)(h2b + (size_t)node * 64 + f0) = o;
            } else {
                int cc = f0 - NC;
                float4 b4 = *(const float4*)(r2b + cc);
                float4 o;
                o.x = acc[0] + b4.x; o.y = acc[1] + b4.y;
                o.z = acc[2] + b4.z; o.w = acc[3] + b4.w;
                *(float4*)(outp + (size_t)node * NC + cc) = o;
            }
        }

        if (wv == 0) {
            f32x4 acc2 = (f32x4){0.f, 0.f, 0.f, 0.f};
            #pragma unroll
            for (int kk = 0; kk < 4; kk++)
                acc2 = __builtin_amdgcn_mfma_f32_16x16x32_bf16(av[kk], wf[kk], acc2, 0, 0, 0);
            if (m < 2) {
                float* dst = (m == 0) ? as2 : ad2;
                #pragma unroll
                for (int r = 0; r < 4; r++) {
                    int nn = nb + ng * 16 + q * 4 + r;
                    if (nn < Nn) dst[nn] = acc2[r];
                }
            }
        }
    }
}

// ---------------- layer 2 gather-aggregate: full pipeline + log_softmax ----------------

__global__ __launch_bounds__(256) void agg2_kernel(
        const int* __restrict__ rs, const int* __restrict__ csr,
        const float* __restrict__ as, const float* __restrict__ ad,
        const unsigned short* __restrict__ h2b, const float* __restrict__ b2,
        float* __restrict__ outp) {
    int lane = threadIdx.x & 63, wv = threadIdx.x >> 6;
    int n = blockIdx.x * 4 + wv;
    if (n >= Nn) return;
    int row = rs[n], end = rs[n + 1];
    float adn = ad[n];
    int slot = lane >> 3, h = lane & 7;
    const unsigned short* hcol = h2b + h * 8;

    float a[8];
    #pragma unroll
    for (int i = 0; i < 8; i++) a[i] = 0.f;
    float den = 0.f;

    // prologue: issue csr/as AND payload loads for chunk 0
    bool v = slot < end - row;
    int sl = v ? csr[row + slot] : 0;
    float asv = as[sl];
    u32x4 cu0 = *(const u32x4*)(hcol + (size_t)sl * 64);

    for (int j = row; j < end; j += 8) {
        bool cv = v;
        float casv = asv;
        u32x4 u0 = cu0;
        int jn = j + 8;
        if (jn < end) {
            v = slot < end - jn;
            sl = v ? csr[jn + slot] : 0;
            asv = as[sl];
            cu0 = *(const u32x4*)(hcol + (size_t)sl * 64);
        }
        float lg = casv + adn;
        lg = fmaxf(lg, SLOPE * lg);
        float e = cv ? __expf(lg) : 0.f;
        den += e;
        #pragma unroll
        for (int k = 0; k < 4; k++) {
            unsigned u = u0[k];
            a[2 * k]     += e * __uint_as_float(u << 16);
            a[2 * k + 1] += e * __uint_as_float(u & 0xffff0000u);
        }
    }

    den += __shfl_xor(den, 8, 64);
    den += __shfl_xor(den, 16, 64);
    den += __shfl_xor(den, 32, 64);
    float inv = 1.f / den;

    int l3 = (lane >> 3) & 1, l4 = (lane >> 4) & 1, l5 = (lane >> 5) & 1;
    float c4[4];
    #pragma unroll
    for (int i = 0; i < 4; i++) {
        float mine = l3 ? a[i + 4] : a[i];
        float send = l3 ? a[i] : a[i + 4];
        c4[i] = mine + __shfl_xor(send, 8, 64);
    }
    float c2[2];
    #pragma unroll
    for (int i = 0; i < 2; i++) {
        float mine = l4 ? c4[i + 2] : c4[i];
        float send = l4 ? c4[i] : c4[i + 2];
        c2[i] = mine + __shfl_xor(send, 16, 64);
    }
    float mine = l5 ? c2[1] : c2[0];
    float send = l5 ? c2[0] : c2[1];
    float av = mine + __shfl_xor(send, 32, 64);
    int c = h * 8 + l3 * 4 + l4 * 2 + l5;
    bool act = c < NC;

    float v0 = -3.4e38f;
    if (act) v0 = av * inv + b2[c] + outp[(size_t)n * NC + c];
    float mm = v0;
    #pragma unroll
    for (int st = 32; st >= 1; st >>= 1) mm = fmaxf(mm, __shfl_xor(mm, st, 64));
    float ex = act ? __expf(v0 - mm) : 0.f;
    float ss = ex;
    #pragma unroll
    for (int st = 32; st >= 1; st >>= 1) ss += __shfl_xor(ss, st, 64);
    if (act) {
        float lg = mm + logf(ss);
        outp[(size_t)n * NC + c] = v0 - lg;
    }
}

// ---------------- host ----------------

extern "C" void kernel_launch(void* const* d_in, const int* in_sizes, int n_in,
                              void* d_out, int out_size, void* d_ws, size_t ws_size,
                              hipStream_t stream) {
    const float* x      = (const float*)d_in[0];
    const int*   ei     = (const int*)d_in[1];
    const float* W1     = (const float*)d_in[2];
    const float* att_s1 = (const float*)d_in[3];
    const float* att_d1 = (const float*)d_in[4];
    const float* bias1  = (const float*)d_in[5];
    const float* W2     = (const float*)d_in[6];
    const float* att_s2 = (const float*)d_in[7];
    const float* att_d2 = (const float*)d_in[8];
    const float* bias2  = (const float*)d_in[9];
    const float* r1W    = (const float*)d_in[10];
    const float* r1b    = (const float*)d_in[11];
    const float* r2W    = (const float*)d_in[12];
    const float* r2b    = (const float*)d_in[13];
    float* out = (float*)d_out;

    float* ws   = (float*)d_ws;
    float* as1  = ws;                            // N*8
    float* ad1  = as1 + (size_t)Nn * 8;          // N*8
    float* as2  = ad1 + (size_t)Nn * 8;          // N
    float* ad2  = as2 + Nn;                      // N
    float* wts  = ad2 + Nn;                      // 128
    float* wtd  = wts + 128;                     // 128
    unsigned short* wtsb = (unsigned short*)(wtd + 128);   // 128 bf16
    unsigned short* wtdb = wtsb + 128;                     // 128 bf16
    unsigned short* hbufb = wtdb + 128;                    // N*128 bf16 (res1)
    unsigned short* h1b = hbufb + (size_t)Nn * 128;        // N*128 bf16
    unsigned short* hb  = h1b + (size_t)Nn * 128;          // N*128 bf16 (post-agg1 h)
    unsigned short* Wb1t = hb + (size_t)Nn * 128;          // 256*128 bf16
    unsigned short* Wb2t = Wb1t + 256 * 128;               // 80*128 bf16
    unsigned short* xb   = Wb2t + 80 * 128;                // N*128 bf16 (pre-cast x)
    uintptr_t pal = ((uintptr_t)(xb + (size_t)Nn * 128) + 15) & ~(uintptr_t)15;
    long long* pairs = (long long*)pal;          // NBUK*CAPB pairs (dead after partB)
    unsigned short* h2b = (unsigned short*)pal;  // N*64 bf16, ALIASES pairs (used after partB)
    int* rs      = (int*)(pairs + (size_t)NBUK * CAPB);  // N+1
    int* bukcnt  = rs + Nn + 1;                  // NBUK
    int* csr     = bukcnt + NBUK;                // EP

    // ---- x->bf16 + weight prep + bukcnt zero + rs[Nn] ----
    castW_kernel<<<XCB + (256 * 128 + 80 * 128 + 256 + NBUK + 1 + 255) / 256, 256, 0, stream>>>(
        x, xb, W1, r1W, W2, r2W, att_s2, att_d2, Wb1t, Wb2t, wts, wtd, wtsb, wtdb, bukcnt, rs);

    // ---- partA || gemm1 (independent, overlapped) ----
    fused1_kernel<<<NBA + G1B, 256, 0, stream>>>(xb, Wb1t, r1b, att_s1, att_d1,
                                                 h1b, hbufb, as1, ad1,
                                                 ei, bukcnt, pairs);

    // ---- CSR finalize ----
    partB_kernel<<<NBUK, 1024, 0, stream>>>(pairs, bukcnt, rs, csr);

    // ---- layer 1 aggregate ----
    agg1_kernel<<<(Nn + 3) / 4, 256, 0, stream>>>(rs, csr, as1, ad1, h1b, bias1,
                                                  hbufb, hb);

    // ---- layer 2 (as2/ad2 computed in-GEMM via extra MFMA) ----
    gemm2_kernel<<<(Nn + 63) / 64, 320, 0, stream>>>(hb, Wb2t, r2b, wtsb, wtdb,
                                                     h2b, out, as2, ad2);
    agg2_kernel<<<(Nn + 3) / 4, 256, 0, stream>>>(rs, csr, as2, ad2, h2b, bias2, out);
}